// Round 4
// baseline (552.964 us; speedup 1.0000x reference)
//
#include <hip/hip_runtime.h>
#include <hip/hip_bf16.h>

// Problem constants (reference setup_inputs)
#define NN   5000   // nodes
#define EDIM 64     // embedding dim
#define DINC 32     // DIN
#define BB   16     // batch
#define LAGN 12     // LAG
#define BC   512    // BB*DINC
#define KPAD 5120   // k-extent padded to 128-tile multiple (zeros in [5000,5120))

typedef __attribute__((ext_vector_type(8))) short short8;   // 8 bf16 = 4 VGPRs
typedef __attribute__((ext_vector_type(4))) float float4v;  // MFMA 16x16 C/D

static __device__ __forceinline__ ushort f2bf(float x) {
  __hip_bfloat16 h = __float2bfloat16(x);
  return *reinterpret_cast<ushort*>(&h);
}
static __device__ __forceinline__ float bf2f(ushort u) {
  unsigned int x = ((unsigned int)u) << 16;
  return __uint_as_float(x);
}
static __device__ __forceinline__ short8 cvt8(const float* p) {  // 8 floats -> bf16x8
  const float4 v0 = *(const float4*)p, v1 = *(const float4*)(p + 4);
  short8 r;
  r[0] = (short)f2bf(v0.x); r[1] = (short)f2bf(v0.y);
  r[2] = (short)f2bf(v0.z); r[3] = (short)f2bf(v0.w);
  r[4] = (short)f2bf(v1.x); r[5] = (short)f2bf(v1.y);
  r[6] = (short)f2bf(v1.z); r[7] = (short)f2bf(v1.w);
  return r;
}

// async global->LDS DMA, 16 B per lane; LDS dst is wave-uniform base + lane*16.
static __device__ __forceinline__ void gll16(const ushort* g, ushort* l) {
  __builtin_amdgcn_global_load_lds(
      (const __attribute__((address_space(1))) void*)g,
      (__attribute__((address_space(3))) void*)l, 16, 0, 0);
}

// ---------------------------------------------------------------------------
// K1: A = relu(emb @ emb^T), [NN, NN] fp32, row-major stride NN.
// ---------------------------------------------------------------------------
__global__ __launch_bounds__(256) void build_A_kernel(const float* __restrict__ emb,
                                                      float* __restrict__ A) {
  __shared__ float Er[64][EDIM + 1];
  __shared__ float Ec[64][EDIM + 1];
  const int row0 = blockIdx.y * 64, col0 = blockIdx.x * 64;
  const int tid = threadIdx.y * 16 + threadIdx.x;
  for (int i = tid; i < 1024; i += 256) {
    const int r = i >> 4, d4 = (i & 15) << 2;
    const int gr = row0 + r, gc = col0 + r;
    float4 v = make_float4(0.f, 0.f, 0.f, 0.f);
    float4 w = make_float4(0.f, 0.f, 0.f, 0.f);
    if (gr < NN) v = *(const float4*)(emb + gr * EDIM + d4);
    if (gc < NN) w = *(const float4*)(emb + gc * EDIM + d4);
    Er[r][d4 + 0] = v.x; Er[r][d4 + 1] = v.y; Er[r][d4 + 2] = v.z; Er[r][d4 + 3] = v.w;
    Ec[r][d4 + 0] = w.x; Ec[r][d4 + 1] = w.y; Ec[r][d4 + 2] = w.z; Ec[r][d4 + 3] = w.w;
  }
  __syncthreads();
  const int ty = threadIdx.y, tx = threadIdx.x;
  float acc[4][4] = {};
  for (int d = 0; d < EDIM; ++d) {
    float a[4], b[4];
#pragma unroll
    for (int r = 0; r < 4; ++r) a[r] = Er[ty + r * 16][d];
#pragma unroll
    for (int c = 0; c < 4; ++c) b[c] = Ec[tx + c * 16][d];
#pragma unroll
    for (int r = 0; r < 4; ++r)
#pragma unroll
      for (int c = 0; c < 4; ++c) acc[r][c] = fmaf(a[r], b[c], acc[r][c]);
  }
#pragma unroll
  for (int r = 0; r < 4; ++r) {
    const int gr = row0 + ty + r * 16;
    if (gr >= NN) continue;
#pragma unroll
    for (int c = 0; c < 4; ++c) {
      const int gc = col0 + tx + c * 16;
      if (gc < NN) A[(size_t)gr * NN + gc] = fmaxf(acc[r][c], 0.f);
    }
  }
}

// ---------------------------------------------------------------------------
// K2: fused row-softmax -> bf16 P, IN PLACE over A. Row m: ushorts [0,5120)
// hold P (+k-pad zeros); ushorts [5128, 9224) are reserved for 8 split-K
// bf16 partial slabs of 512.
// ---------------------------------------------------------------------------
__global__ __launch_bounds__(256) void convert_P_kernel(float* __restrict__ A) {
  const int m = blockIdx.x;
  float* row = A + (size_t)m * NN;
  __shared__ float buf[NN];
  __shared__ float red[256];
  const int tid = threadIdx.x;
  float mx = 0.f;  // relu >= 0, diag > 0
  for (int i = tid; i < 1250; i += 256) {
    float4 v = *(const float4*)(row + i * 4);
    *(float4*)(buf + i * 4) = v;
    mx = fmaxf(mx, fmaxf(fmaxf(v.x, v.y), fmaxf(v.z, v.w)));
  }
  red[tid] = mx; __syncthreads();
  for (int s = 128; s > 0; s >>= 1) {
    if (tid < s) red[tid] = fmaxf(red[tid], red[tid + s]);
    __syncthreads();
  }
  mx = red[0]; __syncthreads();
  float sum = 0.f;
  for (int i = tid; i < 1250; i += 256) {
    float4 v = *(const float4*)(buf + i * 4);
    v.x = __expf(v.x - mx); v.y = __expf(v.y - mx);
    v.z = __expf(v.z - mx); v.w = __expf(v.w - mx);
    *(float4*)(buf + i * 4) = v;
    sum += v.x + v.y + v.z + v.w;
  }
  red[tid] = sum; __syncthreads();
  for (int s = 128; s > 0; s >>= 1) {
    if (tid < s) red[tid] += red[tid + s];
    __syncthreads();
  }
  const float inv = 1.f / red[0];
  ushort* prow = (ushort*)row;
  for (int i = tid; i < 1250; i += 256) {
    float4 v = *(const float4*)(buf + i * 4);
    ushort4 o;
    o.x = f2bf(v.x * inv); o.y = f2bf(v.y * inv);
    o.z = f2bf(v.z * inv); o.w = f2bf(v.w * inv);
    *(ushort4*)(prow + i * 4) = o;
  }
  if (tid < 120) prow[5000 + tid] = 0;  // k-pad zeros
}

// ---------------------------------------------------------------------------
// K3: XbT[b*32+c][m] = bf16(x[b][m][c]); [512][KPAD] bf16, zero pad m>=5000.
// ---------------------------------------------------------------------------
__global__ __launch_bounds__(256) void transpose_xb_kernel(const float* __restrict__ x,
                                                           ushort* __restrict__ XbT) {
  const int m = blockIdx.x * 256 + threadIdx.x;  // 0..5119
  const int j = blockIdx.y;                      // 0..511
  const int b = j >> 5, c = j & 31;
  ushort v = 0;
  if (m < NN) v = f2bf(x[((size_t)b * NN + m) * DINC + c]);
  XbT[(size_t)j * KPAD + m] = v;
}

// ---------------------------------------------------------------------------
// K4/K6: bf16 MFMA GEMM. BM=BN=128, BK=32, 256 thr = 4 waves (2x2 of 64x64).
// Split-K=8 (blockIdx.z, k-chunk 640 = 20 iters) -> grid 1280 = 5 blocks/CU.
// LDS chunk-major [kq][row][8 bf16] (achieved by lane->granule permutation in
// the DMA pointers): frag ds_read_b128 banks = 4*row%32 -> conflict-free.
// bf16 partials stored in each P row's free half:
//   ushort index m*10000 + 5128 + z*512 + col.
// ---------------------------------------------------------------------------
__global__ __launch_bounds__(256) void mfma_gemm_kernel(const ushort* __restrict__ Pm,
                                                        const ushort* __restrict__ Bt,
                                                        ushort* __restrict__ Pp) {
  __shared__ __align__(16) ushort As[4096];  // chunk-major [4][128][8]
  __shared__ __align__(16) ushort Bs[4096];
  const int tid = threadIdx.x;
  const int w = tid >> 6, l = tid & 63;
  const int fm = l & 15, kq = l >> 4;
  const int wm = w >> 1, wn = w & 1;
  const int row0 = blockIdx.y * 128, col0 = blockIdx.x * 128;
  const int kbase = blockIdx.z * 640;
  // lane -> granule: LDS slot p=tid holds (chunk=tid>>7, row=tid&127)
  const int ra = tid & 127, ch = tid >> 7;   // ch in {0,1}; second call = ch+2
  const ushort* gA0 = Pm + (size_t)(row0 + ra) * 10000 + kbase + ch * 8;
  const ushort* gA1 = gA0 + 16;
  const ushort* gB0 = Bt + (size_t)(col0 + ra) * KPAD + kbase + ch * 8;
  const ushort* gB1 = gB0 + 16;
  ushort* lA0 = As + tid * 8;  ushort* lA1 = As + (tid + 256) * 8;
  ushort* lB0 = Bs + tid * 8;  ushort* lB1 = Bs + (tid + 256) * 8;
  int aoff[4], boff[4];
#pragma unroll
  for (int mt = 0; mt < 4; ++mt) aoff[mt] = (kq * 128 + wm * 64 + mt * 16 + fm) * 8;
#pragma unroll
  for (int nt = 0; nt < 4; ++nt) boff[nt] = (kq * 128 + wn * 64 + nt * 16 + fm) * 8;
  float4v acc[4][4] = {};
  for (int kt = 0; kt < 20; ++kt) {
    const int k0 = kt * 32;
    __syncthreads();  // prior-iter frag reads done before DMA overwrites LDS
    gll16(gA0 + k0, lA0);
    gll16(gA1 + k0, lA1);
    gll16(gB0 + k0, lB0);
    gll16(gB1 + k0, lB1);
    __syncthreads();  // vmcnt(0) drained before barrier -> LDS ready
    short8 a[4], b[4];
#pragma unroll
    for (int mt = 0; mt < 4; ++mt) a[mt] = *(const short8*)(As + aoff[mt]);
#pragma unroll
    for (int nt = 0; nt < 4; ++nt) b[nt] = *(const short8*)(Bs + boff[nt]);
#pragma unroll
    for (int mt = 0; mt < 4; ++mt)
#pragma unroll
      for (int nt = 0; nt < 4; ++nt)
        acc[mt][nt] = __builtin_amdgcn_mfma_f32_16x16x32_bf16(a[mt], b[nt], acc[mt][nt], 0, 0, 0);
  }
  // epilogue: bf16 partials into the P rows' free halves
  const int cb = col0 + wn * 64 + fm;
  const int zoff = 5128 + blockIdx.z * 512;
#pragma unroll
  for (int mt = 0; mt < 4; ++mt)
#pragma unroll
    for (int r = 0; r < 4; ++r) {
      const int gm = row0 + wm * 64 + mt * 16 + kq * 4 + r;
      if (gm < NN) {
        ushort* prow = Pp + (size_t)gm * 10000 + zoff + cb;
#pragma unroll
        for (int nt = 0; nt < 4; ++nt) prow[nt * 16] = f2bf(acc[mt][nt][r]);
      }
    }
}

// ---------------------------------------------------------------------------
// K5/K7: sum 8 bf16 split-K partials -> Yf fp32 [5000][512]; optionally also
// Yt bf16 [512][KPAD] (transposed, zero pad m in [5000,5120)). Grid (8,80).
// ---------------------------------------------------------------------------
__global__ __launch_bounds__(256) void reduce_kernel(const ushort* __restrict__ Pp,
                                                     float* __restrict__ Yf,
                                                     ushort* __restrict__ Yt,
                                                     int writeT) {
  const int m0 = blockIdx.y * 64, n0 = blockIdx.x * 64;
  __shared__ __align__(16) ushort Lt[64][80];  // [n][m]
  const int tid = threadIdx.x;
  const int mi = tid >> 4, nl4 = (tid & 15) << 2;
#pragma unroll
  for (int s = 0; s < 4; ++s) {
    const int m = m0 + mi + s * 16;
    float4 sum = make_float4(0.f, 0.f, 0.f, 0.f);
    if (m < NN) {
      const ushort* pr = Pp + (size_t)m * 10000 + 5128 + n0 + nl4;
#pragma unroll
      for (int z = 0; z < 8; ++z) {
        ushort4 u = *(const ushort4*)(pr + z * 512);
        sum.x += bf2f(u.x); sum.y += bf2f(u.y);
        sum.z += bf2f(u.z); sum.w += bf2f(u.w);
      }
      *(float4*)(Yf + (size_t)m * BC + n0 + nl4) = sum;
    }
    if (writeT) {
      const int ml = mi + s * 16;
      Lt[nl4 + 0][ml] = f2bf(sum.x);
      Lt[nl4 + 1][ml] = f2bf(sum.y);
      Lt[nl4 + 2][ml] = f2bf(sum.z);
      Lt[nl4 + 3][ml] = f2bf(sum.w);
    }
  }
  if (writeT) {
    __syncthreads();
#pragma unroll
    for (int i = 0; i < 2; ++i) {
      const int g = tid + i * 256;
      const int nl = g >> 3, gi = g & 7;
      *(uint4*)(Yt + (size_t)(n0 + nl) * KPAD + m0 + gi * 8) =
          *(const uint4*)(&Lt[nl][gi * 8]);
    }
  }
}

// ---------------------------------------------------------------------------
// K8/K9: Wt/wwt = emb @ permuted(weights_pool) -> bf16, fuse-friendly layout:
//   mode 0 (Ncp=3072): out col c' = o*96 + kk*32 + i  <- src col kk*1024+i*32+o
//   mode 1 (Ncp=512) : out col c' = o*16 + i          <- src col i*32+o
// ---------------------------------------------------------------------------
__global__ __launch_bounds__(256) void emb_gemm_perm_kernel(const float* __restrict__ Ae,
                                                            const float* __restrict__ Bw,
                                                            ushort* __restrict__ C,
                                                            int Ncp, int mode) {
  __shared__ float Aet[EDIM][32];
  __shared__ float Bs[EDIM][64];
  const int row0 = blockIdx.y * 32, col0 = blockIdx.x * 64;
  const int tid = threadIdx.x;
  for (int i = tid; i < 512; i += 256) {
    const int r = i >> 4, d4 = (i & 15) << 2;
    const int gm = row0 + r;
    float4 v = make_float4(0.f, 0.f, 0.f, 0.f);
    if (gm < NN) v = *(const float4*)(Ae + (size_t)gm * EDIM + d4);
    Aet[d4 + 0][r] = v.x; Aet[d4 + 1][r] = v.y; Aet[d4 + 2][r] = v.z; Aet[d4 + 3][r] = v.w;
  }
  for (int i = tid; i < 4096; i += 256) {
    const int d = i >> 6, j = i & 63;
    const int cp = col0 + j;
    int c;
    if (mode == 0) {
      const int o = cp / 96, r96 = cp - o * 96;
      c = ((r96 >> 5) << 10) + ((r96 & 31) << 5) + o;
    } else {
      c = ((cp & 15) << 5) + (cp >> 4);
    }
    Bs[d][j] = Bw[(size_t)d * Ncp + c];
  }
  __syncthreads();
  const int ty = tid >> 4, tx = tid & 15;
  float acc[2][4] = {};
#pragma unroll 8
  for (int d = 0; d < EDIM; ++d) {
    const float a0 = Aet[d][ty * 2], a1 = Aet[d][ty * 2 + 1];
    const float4 b4 = *(const float4*)&Bs[d][tx << 2];
    acc[0][0] = fmaf(a0, b4.x, acc[0][0]); acc[0][1] = fmaf(a0, b4.y, acc[0][1]);
    acc[0][2] = fmaf(a0, b4.z, acc[0][2]); acc[0][3] = fmaf(a0, b4.w, acc[0][3]);
    acc[1][0] = fmaf(a1, b4.x, acc[1][0]); acc[1][1] = fmaf(a1, b4.y, acc[1][1]);
    acc[1][2] = fmaf(a1, b4.z, acc[1][2]); acc[1][3] = fmaf(a1, b4.w, acc[1][3]);
  }
#pragma unroll
  for (int r = 0; r < 2; ++r) {
    const int gm = row0 + ty * 2 + r;
    if (gm >= NN) continue;
    ushort4 o4;
    o4.x = f2bf(acc[r][0]); o4.y = f2bf(acc[r][1]);
    o4.z = f2bf(acc[r][2]); o4.w = f2bf(acc[r][3]);
    *(ushort4*)(C + (size_t)gm * Ncp + col0 + (tx << 2)) = o4;
  }
}

// ---------------------------------------------------------------------------
// K10: biasN fp32 = emb @ bias_pool  (Nc=64)
// ---------------------------------------------------------------------------
__global__ __launch_bounds__(256) void emb_gemm_kernel(const float* __restrict__ Ae,
                                                       const float* __restrict__ Bw,
                                                       float* __restrict__ C,
                                                       int M, int Nc) {
  __shared__ float Aet[EDIM][32];
  __shared__ __align__(16) float Bs[EDIM][64];
  const int row0 = blockIdx.y * 32, col0 = blockIdx.x * 64;
  const int tid = threadIdx.x;
  for (int i = tid; i < 512; i += 256) {
    const int r = i >> 4, d4 = (i & 15) << 2;
    const int gm = row0 + r;
    float4 v = make_float4(0.f, 0.f, 0.f, 0.f);
    if (gm < M) v = *(const float4*)(Ae + (size_t)gm * EDIM + d4);
    Aet[d4 + 0][r] = v.x; Aet[d4 + 1][r] = v.y; Aet[d4 + 2][r] = v.z; Aet[d4 + 3][r] = v.w;
  }
  for (int i = tid; i < 1024; i += 256) {
    const int br = i >> 4, bc = (i & 15) << 2;
    if (bc < Nc) *(float4*)&Bs[br][bc] = *(const float4*)(Bw + (size_t)br * Nc + bc);
  }
  __syncthreads();
  const int ty = tid >> 4, tx = tid & 15;
  float acc[2][4] = {};
#pragma unroll 8
  for (int d = 0; d < EDIM; ++d) {
    const float a0 = Aet[d][ty * 2], a1 = Aet[d][ty * 2 + 1];
    const float4 b4 = *(const float4*)&Bs[d][tx << 2];
    acc[0][0] = fmaf(a0, b4.x, acc[0][0]); acc[0][1] = fmaf(a0, b4.y, acc[0][1]);
    acc[0][2] = fmaf(a0, b4.z, acc[0][2]); acc[0][3] = fmaf(a0, b4.w, acc[0][3]);
    acc[1][0] = fmaf(a1, b4.x, acc[1][0]); acc[1][1] = fmaf(a1, b4.y, acc[1][1]);
    acc[1][2] = fmaf(a1, b4.z, acc[1][2]); acc[1][3] = fmaf(a1, b4.w, acc[1][3]);
  }
#pragma unroll
  for (int r = 0; r < 2; ++r) {
    const int gm = row0 + ty * 2 + r;
    if (gm >= M) continue;
    float4 o;
    o.x = acc[r][0]; o.y = acc[r][1]; o.z = acc[r][2]; o.w = acc[r][3];
    *(float4*)(C + (size_t)gm * Nc + col0 + (tx << 2)) = o;
  }
}

// ---------------------------------------------------------------------------
// K11: xwc[b, n, i] = sum_t T[t] * x_window[b, t, n, i]
// ---------------------------------------------------------------------------
__global__ __launch_bounds__(256) void window_combine_kernel(const float* __restrict__ xw,
                                                             const float* __restrict__ T,
                                                             float* __restrict__ out) {
  const int idx = blockIdx.x * 256 + threadIdx.x;
  if (idx >= BB * NN * 16) return;
  const int b = idx / (NN * 16);
  const int rem = idx - b * (NN * 16);
  float acc = 0.f;
#pragma unroll
  for (int t = 0; t < LAGN; ++t)
    acc = fmaf(T[t], xw[(size_t)(b * LAGN + t) * (NN * 16) + rem], acc);
  out[idx] = acc;
}

// ---------------------------------------------------------------------------
// K12: MFMA fusion. One wave per node: gconv = [16b x 96k] @ Wt[n] (3 chunks
// x 2 o-tiles = 6 MFMAs), wconv = [16b x 16k(pad32)] @ wwt[n] (2 MFMAs).
// C/D: col(lane&15)=o, row(quad*4+reg)=b. LN over o via 16-lane butterflies
// across both o-tiles. A-frags: lane(fm=b, kq) reads 8 consecutive k fp32 ->
// bf16. B-frags: lane(fm=o, kq) reads Wt[n][o][chunk*32+kq*8..+8] (16 B).
// ---------------------------------------------------------------------------
__global__ __launch_bounds__(256) void fuse_mfma_kernel(const float* __restrict__ x,
                                                        const float* __restrict__ Y1f,
                                                        const float* __restrict__ Y2f,
                                                        const ushort* __restrict__ Wt,
                                                        const ushort* __restrict__ wwt,
                                                        const float* __restrict__ biasN,
                                                        const float* __restrict__ xwc,
                                                        const float* __restrict__ ln1w,
                                                        const float* __restrict__ ln1b,
                                                        const float* __restrict__ ln2w,
                                                        const float* __restrict__ ln2b,
                                                        float* __restrict__ out) {
  const int tid = threadIdx.x;
  const int n = blockIdx.x * 4 + (tid >> 6);  // grid 1250*4 = 5000 exact
  const int l = tid & 63, fm = l & 15, kq = l >> 4;
  // A fragments
  const short8 ax = cvt8(x + ((size_t)fm * NN + n) * DINC + kq * 8);
  const short8 a1 = cvt8(Y1f + (size_t)n * BC + fm * 32 + kq * 8);
  const short8 a2 = cvt8(Y2f + (size_t)n * BC + fm * 32 + kq * 8);
  short8 aw = {};
  if (kq < 2) aw = cvt8(xwc + ((size_t)fm * NN + n) * 16 + kq * 8);
  const ushort* wn = Wt + (size_t)n * 3072;
  const ushort* wwn = wwt + (size_t)n * 512;
  float4v accG[2] = {}, accW[2] = {};
#pragma unroll
  for (int t = 0; t < 2; ++t) {
    const int ob = (t * 16 + fm) * 96 + kq * 8;
    const short8 b0 = *(const short8*)(wn + ob);
    const short8 b1 = *(const short8*)(wn + ob + 32);
    const short8 b2 = *(const short8*)(wn + ob + 64);
    accG[t] = __builtin_amdgcn_mfma_f32_16x16x32_bf16(ax, b0, accG[t], 0, 0, 0);
    accG[t] = __builtin_amdgcn_mfma_f32_16x16x32_bf16(a1, b1, accG[t], 0, 0, 0);
    accG[t] = __builtin_amdgcn_mfma_f32_16x16x32_bf16(a2, b2, accG[t], 0, 0, 0);
    short8 bw = {};
    if (kq < 2) bw = *(const short8*)(wwn + (t * 16 + fm) * 16 + kq * 8);
    accW[t] = __builtin_amdgcn_mfma_f32_16x16x32_bf16(aw, bw, accW[t], 0, 0, 0);
  }
  const float w1a = ln1w[fm], w1b = ln1w[16 + fm];
  const float c1a = ln1b[fm], c1b = ln1b[16 + fm];
  const float w2a = ln2w[fm], w2b = ln2w[16 + fm];
  const float c2a = ln2b[fm], c2b = ln2b[16 + fm];
  const float* bn = biasN + (size_t)n * 64;
  const float bga = bn[fm], bgb = bn[16 + fm];
  const float bwa = bn[32 + fm], bwb = bn[48 + fm];
#pragma unroll
  for (int r = 0; r < 4; ++r) {
    const int b = kq * 4 + r;
    const float g0 = accG[0][r], g1 = accG[1][r];
    float s1 = g0 + g1, s2 = g0 * g0 + g1 * g1;
#pragma unroll
    for (int m = 1; m < 16; m <<= 1) { s1 += __shfl_xor(s1, m); s2 += __shfl_xor(s2, m); }
    const float mu = s1 * 0.03125f;
    const float rs = rsqrtf(s2 * 0.03125f - mu * mu + 1e-5f);
    const float h0 = accW[0][r], h1 = accW[1][r];
    float t1 = h0 + h1, t2 = h0 * h0 + h1 * h1;
#pragma unroll
    for (int m = 1; m < 16; m <<= 1) { t1 += __shfl_xor(t1, m); t2 += __shfl_xor(t2, m); }
    const float mu2 = t1 * 0.03125f;
    const float rs2 = rsqrtf(t2 * 0.03125f - mu2 * mu2 + 1e-5f);
    float* op = out + ((size_t)b * NN + n) * 64;
    op[fm]      = (g0 - mu) * rs * w1a + c1a + bga;
    op[16 + fm] = (g1 - mu) * rs * w1b + c1b + bgb;
    op[32 + fm] = (h0 - mu2) * rs2 * w2a + c2a + bwa;
    op[48 + fm] = (h1 - mu2) * rs2 * w2b + c2b + bwb;
  }
}

// ---------------------------------------------------------------------------
// Workspace map (fp32 slots), high-water 30,181,440 floats = 120.7 MB:
//   [0, 25M)             A fp32 -> P bf16 (row = 10000 ushorts: [0,5120) P+pad,
//                        [5128,9224) 8 bf16 split-K partial slabs)
//                        -> after reduce2: overlaid by Wt/wwt/biasN/xwc
//   [25.0M, 26.31072M)   XbT bf16 [512][5120]   (dead after GEMM1)
//   [26.31072M,27.62144M) Y1t bf16 [512][5120]  (dead after GEMM2)
//   [25.0M, 27.56M)      Y2f fp32 (reduce2 output, overlays XbT+Y1t)
//   [27.62144M,30.18144M) Y1f fp32
// ---------------------------------------------------------------------------
extern "C" void kernel_launch(void* const* d_in, const int* in_sizes, int n_in,
                              void* d_out, int out_size, void* d_ws, size_t ws_size,
                              hipStream_t stream) {
  const float* x     = (const float*)d_in[0];
  const float* xwin  = (const float*)d_in[1];
  const float* emb   = (const float*)d_in[2];
  const float* wpool = (const float*)d_in[3];
  const float* wwin  = (const float*)d_in[4];
  const float* bpool = (const float*)d_in[5];
  const float* T     = (const float*)d_in[6];
  const float* ln1w  = (const float*)d_in[7];
  const float* ln1b  = (const float*)d_in[8];
  const float* ln2w  = (const float*)d_in[9];
  const float* ln2b  = (const float*)d_in[10];
  float* out = (float*)d_out;
  float* ws = (float*)d_ws;

  float*  A    = ws;
  ushort* P    = (ushort*)ws;
  ushort* XbT  = (ushort*)(ws + 25000000);
  ushort* Y1t  = (ushort*)(ws + 26310720);
  float*  Y1f  = ws + 27621440;
  float*  Y2f  = ws + 25000000;        // overlays XbT+Y1t after GEMM2
  ushort* Wt    = (ushort*)ws;         // [5000][3072] bf16, overlays P after reduce2
  ushort* wwt   = (ushort*)(ws + 15360000);  // [5000][512] bf16
  float*  biasN = ws + 17920000;
  float*  xwc   = ws + 18240000;

  build_A_kernel<<<dim3(79, 79), dim3(16, 16), 0, stream>>>(emb, A);
  convert_P_kernel<<<NN, 256, 0, stream>>>(A);
  transpose_xb_kernel<<<dim3(20, 512), 256, 0, stream>>>(x, XbT);
  mfma_gemm_kernel<<<dim3(4, 40, 8), 256, 0, stream>>>(P, XbT, P);
  reduce_kernel<<<dim3(8, 80), 256, 0, stream>>>(P, Y1f, Y1t, 1);
  mfma_gemm_kernel<<<dim3(4, 40, 8), 256, 0, stream>>>(P, Y1t, P);
  reduce_kernel<<<dim3(8, 80), 256, 0, stream>>>(P, Y2f, (ushort*)nullptr, 0);
  emb_gemm_perm_kernel<<<dim3(48, 157), 256, 0, stream>>>(emb, wpool, Wt, 3072, 0);
  emb_gemm_perm_kernel<<<dim3(8, 157), 256, 0, stream>>>(emb, wwin, wwt, 512, 1);
  emb_gemm_kernel<<<dim3(1, 157), 256, 0, stream>>>(emb, bpool, biasN, NN, 64);
  window_combine_kernel<<<(BB * NN * 16 + 255) / 256, 256, 0, stream>>>(xwin, T, xwc);
  fuse_mfma_kernel<<<1250, 256, 0, stream>>>(x, Y1f, Y2f, Wt, wwt, biasN, xwc,
                                             ln1w, ln1b, ln2w, ln2b, out);
}

// Round 5
// 469.588 us; speedup vs baseline: 1.1776x; 1.1776x over previous
//
#include <hip/hip_runtime.h>
#include <hip/hip_bf16.h>

// Problem constants (reference setup_inputs)
#define NN   5000   // nodes
#define EDIM 64     // embedding dim
#define DINC 32     // DIN
#define BB   16     // batch
#define LAGN 12     // LAG
#define BC   512    // BB*DINC
#define KPAD 5120   // k-extent padded to 128-tile multiple (zeros in [5000,5120))

typedef __attribute__((ext_vector_type(8))) short short8;   // 8 bf16 = 4 VGPRs
typedef __attribute__((ext_vector_type(4))) float float4v;  // MFMA 16x16 C/D

static __device__ __forceinline__ ushort f2bf(float x) {
  __hip_bfloat16 h = __float2bfloat16(x);
  return *reinterpret_cast<ushort*>(&h);
}
static __device__ __forceinline__ float bf2f(ushort u) {
  unsigned int x = ((unsigned int)u) << 16;
  return __uint_as_float(x);
}
static __device__ __forceinline__ short8 cvt8(const float* p) {  // 8 floats -> bf16x8
  const float4 v0 = *(const float4*)p, v1 = *(const float4*)(p + 4);
  short8 r;
  r[0] = (short)f2bf(v0.x); r[1] = (short)f2bf(v0.y);
  r[2] = (short)f2bf(v0.z); r[3] = (short)f2bf(v0.w);
  r[4] = (short)f2bf(v1.x); r[5] = (short)f2bf(v1.y);
  r[6] = (short)f2bf(v1.z); r[7] = (short)f2bf(v1.w);
  return r;
}

// async global->LDS DMA, 16 B per lane; LDS dst is wave-uniform base + lane*16.
static __device__ __forceinline__ void gll16(const ushort* g, ushort* l) {
  __builtin_amdgcn_global_load_lds(
      (const __attribute__((address_space(1))) void*)g,
      (__attribute__((address_space(3))) void*)l, 16, 0, 0);
}

// ---------------------------------------------------------------------------
// K0a: permute wpool [64][3][32][32] (d,kk,i,o) -> wpP [64][3072] with
// col' = o*96 + kk*32 + i. Reads fully coalesced; scatter writes (~786 KB).
// ---------------------------------------------------------------------------
__global__ __launch_bounds__(256) void perm_wpool_kernel(const float* __restrict__ in,
                                                         float* __restrict__ outp) {
  const int t = blockIdx.x * 256 + threadIdx.x;
  if (t >= 64 * 3072) return;
  const int d = t / 3072, r = t - d * 3072;
  const int kk = r >> 10, r2 = r & 1023;
  const int i = r2 >> 5, o = r2 & 31;
  outp[(size_t)d * 3072 + o * 96 + kk * 32 + i] = in[t];
}

// K0b: permute wwin [64][16][32] (d,i,o) -> wwP [64][512], col' = o*16 + i.
__global__ __launch_bounds__(256) void perm_wwin_kernel(const float* __restrict__ in,
                                                        float* __restrict__ outp) {
  const int t = blockIdx.x * 256 + threadIdx.x;
  if (t >= 64 * 512) return;
  const int d = t >> 9, r = t & 511;
  const int i = r >> 5, o = r & 31;
  outp[(size_t)d * 512 + o * 16 + i] = in[t];
}

// ---------------------------------------------------------------------------
// K1: A = relu(emb @ emb^T), [NN, NN] fp32, row-major stride NN.
// ---------------------------------------------------------------------------
__global__ __launch_bounds__(256) void build_A_kernel(const float* __restrict__ emb,
                                                      float* __restrict__ A) {
  __shared__ float Er[64][EDIM + 1];
  __shared__ float Ec[64][EDIM + 1];
  const int row0 = blockIdx.y * 64, col0 = blockIdx.x * 64;
  const int tid = threadIdx.y * 16 + threadIdx.x;
  for (int i = tid; i < 1024; i += 256) {
    const int r = i >> 4, d4 = (i & 15) << 2;
    const int gr = row0 + r, gc = col0 + r;
    float4 v = make_float4(0.f, 0.f, 0.f, 0.f);
    float4 w = make_float4(0.f, 0.f, 0.f, 0.f);
    if (gr < NN) v = *(const float4*)(emb + gr * EDIM + d4);
    if (gc < NN) w = *(const float4*)(emb + gc * EDIM + d4);
    Er[r][d4 + 0] = v.x; Er[r][d4 + 1] = v.y; Er[r][d4 + 2] = v.z; Er[r][d4 + 3] = v.w;
    Ec[r][d4 + 0] = w.x; Ec[r][d4 + 1] = w.y; Ec[r][d4 + 2] = w.z; Ec[r][d4 + 3] = w.w;
  }
  __syncthreads();
  const int ty = threadIdx.y, tx = threadIdx.x;
  float acc[4][4] = {};
  for (int d = 0; d < EDIM; ++d) {
    float a[4], b[4];
#pragma unroll
    for (int r = 0; r < 4; ++r) a[r] = Er[ty + r * 16][d];
#pragma unroll
    for (int c = 0; c < 4; ++c) b[c] = Ec[tx + c * 16][d];
#pragma unroll
    for (int r = 0; r < 4; ++r)
#pragma unroll
      for (int c = 0; c < 4; ++c) acc[r][c] = fmaf(a[r], b[c], acc[r][c]);
  }
#pragma unroll
  for (int r = 0; r < 4; ++r) {
    const int gr = row0 + ty + r * 16;
    if (gr >= NN) continue;
#pragma unroll
    for (int c = 0; c < 4; ++c) {
      const int gc = col0 + tx + c * 16;
      if (gc < NN) A[(size_t)gr * NN + gc] = fmaxf(acc[r][c], 0.f);
    }
  }
}

// ---------------------------------------------------------------------------
// K2: fused row-softmax -> bf16 P, IN PLACE over A. Row m: ushorts [0,5120)
// hold P (+k-pad zeros); ushorts [5128, 9224) hold 8 split-K partial slabs.
// ---------------------------------------------------------------------------
__global__ __launch_bounds__(256) void convert_P_kernel(float* __restrict__ A) {
  const int m = blockIdx.x;
  float* row = A + (size_t)m * NN;
  __shared__ float buf[NN];
  __shared__ float red[256];
  const int tid = threadIdx.x;
  float mx = 0.f;  // relu >= 0, diag > 0
  for (int i = tid; i < 1250; i += 256) {
    float4 v = *(const float4*)(row + i * 4);
    *(float4*)(buf + i * 4) = v;
    mx = fmaxf(mx, fmaxf(fmaxf(v.x, v.y), fmaxf(v.z, v.w)));
  }
  red[tid] = mx; __syncthreads();
  for (int s = 128; s > 0; s >>= 1) {
    if (tid < s) red[tid] = fmaxf(red[tid], red[tid + s]);
    __syncthreads();
  }
  mx = red[0]; __syncthreads();
  float sum = 0.f;
  for (int i = tid; i < 1250; i += 256) {
    float4 v = *(const float4*)(buf + i * 4);
    v.x = __expf(v.x - mx); v.y = __expf(v.y - mx);
    v.z = __expf(v.z - mx); v.w = __expf(v.w - mx);
    *(float4*)(buf + i * 4) = v;
    sum += v.x + v.y + v.z + v.w;
  }
  red[tid] = sum; __syncthreads();
  for (int s = 128; s > 0; s >>= 1) {
    if (tid < s) red[tid] += red[tid + s];
    __syncthreads();
  }
  const float inv = 1.f / red[0];
  ushort* prow = (ushort*)row;
  for (int i = tid; i < 1250; i += 256) {
    float4 v = *(const float4*)(buf + i * 4);
    ushort4 o;
    o.x = f2bf(v.x * inv); o.y = f2bf(v.y * inv);
    o.z = f2bf(v.z * inv); o.w = f2bf(v.w * inv);
    *(ushort4*)(prow + i * 4) = o;
  }
  if (tid < 120) prow[5000 + tid] = 0;  // k-pad zeros
}

// ---------------------------------------------------------------------------
// K3: XbT[b*32+c][m] = bf16(x[b][m][c]); [512][KPAD] bf16, zero pad m>=5000.
// ---------------------------------------------------------------------------
__global__ __launch_bounds__(256) void transpose_xb_kernel(const float* __restrict__ x,
                                                           ushort* __restrict__ XbT) {
  const int m = blockIdx.x * 256 + threadIdx.x;  // 0..5119
  const int j = blockIdx.y;                      // 0..511
  const int b = j >> 5, c = j & 31;
  ushort v = 0;
  if (m < NN) v = f2bf(x[((size_t)b * NN + m) * DINC + c]);
  XbT[(size_t)j * KPAD + m] = v;
}

// ---------------------------------------------------------------------------
// K4/K6: bf16 MFMA GEMM. BM=BN=128, BK=32, 256 thr = 4 waves (2x2 of 64x64).
// Split-K=8 (blockIdx.z, k-chunk 640 = 20 iters) -> grid 1280 = 5 blocks/CU.
// LDS chunk-major [kq][row][8 bf16]: frag ds_read_b128 conflict-free.
// bf16 partials at ushort index m*10000 + 5128 + z*512 + col.
// ---------------------------------------------------------------------------
__global__ __launch_bounds__(256) void mfma_gemm_kernel(const ushort* __restrict__ Pm,
                                                        const ushort* __restrict__ Bt,
                                                        ushort* __restrict__ Pp) {
  __shared__ __align__(16) ushort As[4096];  // chunk-major [4][128][8]
  __shared__ __align__(16) ushort Bs[4096];
  const int tid = threadIdx.x;
  const int w = tid >> 6, l = tid & 63;
  const int fm = l & 15, kq = l >> 4;
  const int wm = w >> 1, wn = w & 1;
  const int row0 = blockIdx.y * 128, col0 = blockIdx.x * 128;
  const int kbase = blockIdx.z * 640;
  const int ra = tid & 127, ch = tid >> 7;   // ch in {0,1}; second call = ch+2
  const ushort* gA0 = Pm + (size_t)(row0 + ra) * 10000 + kbase + ch * 8;
  const ushort* gA1 = gA0 + 16;
  const ushort* gB0 = Bt + (size_t)(col0 + ra) * KPAD + kbase + ch * 8;
  const ushort* gB1 = gB0 + 16;
  ushort* lA0 = As + tid * 8;  ushort* lA1 = As + (tid + 256) * 8;
  ushort* lB0 = Bs + tid * 8;  ushort* lB1 = Bs + (tid + 256) * 8;
  int aoff[4], boff[4];
#pragma unroll
  for (int mt = 0; mt < 4; ++mt) aoff[mt] = (kq * 128 + wm * 64 + mt * 16 + fm) * 8;
#pragma unroll
  for (int nt = 0; nt < 4; ++nt) boff[nt] = (kq * 128 + wn * 64 + nt * 16 + fm) * 8;
  float4v acc[4][4] = {};
  for (int kt = 0; kt < 20; ++kt) {
    const int k0 = kt * 32;
    __syncthreads();  // prior-iter frag reads done before DMA overwrites LDS
    gll16(gA0 + k0, lA0);
    gll16(gA1 + k0, lA1);
    gll16(gB0 + k0, lB0);
    gll16(gB1 + k0, lB1);
    __syncthreads();  // vmcnt(0) drained before barrier -> LDS ready
    short8 a[4], b[4];
#pragma unroll
    for (int mt = 0; mt < 4; ++mt) a[mt] = *(const short8*)(As + aoff[mt]);
#pragma unroll
    for (int nt = 0; nt < 4; ++nt) b[nt] = *(const short8*)(Bs + boff[nt]);
#pragma unroll
    for (int mt = 0; mt < 4; ++mt)
#pragma unroll
      for (int nt = 0; nt < 4; ++nt)
        acc[mt][nt] = __builtin_amdgcn_mfma_f32_16x16x32_bf16(a[mt], b[nt], acc[mt][nt], 0, 0, 0);
  }
  const int cb = col0 + wn * 64 + fm;
  const int zoff = 5128 + blockIdx.z * 512;
#pragma unroll
  for (int mt = 0; mt < 4; ++mt)
#pragma unroll
    for (int r = 0; r < 4; ++r) {
      const int gm = row0 + wm * 64 + mt * 16 + kq * 4 + r;
      if (gm < NN) {
        ushort* prow = Pp + (size_t)gm * 10000 + zoff + cb;
#pragma unroll
        for (int nt = 0; nt < 4; ++nt) prow[nt * 16] = f2bf(acc[mt][nt][r]);
      }
    }
}

// ---------------------------------------------------------------------------
// K5/K7: sum 8 bf16 split-K partials -> Yf fp32 [5000][512]; optionally also
// Yt bf16 [512][KPAD] (transposed, zero pad m in [5000,5120)). Grid (8,80).
// ---------------------------------------------------------------------------
__global__ __launch_bounds__(256) void reduce_kernel(const ushort* __restrict__ Pp,
                                                     float* __restrict__ Yf,
                                                     ushort* __restrict__ Yt,
                                                     int writeT) {
  const int m0 = blockIdx.y * 64, n0 = blockIdx.x * 64;
  __shared__ __align__(16) ushort Lt[64][80];  // [n][m]
  const int tid = threadIdx.x;
  const int mi = tid >> 4, nl4 = (tid & 15) << 2;
#pragma unroll
  for (int s = 0; s < 4; ++s) {
    const int m = m0 + mi + s * 16;
    float4 sum = make_float4(0.f, 0.f, 0.f, 0.f);
    if (m < NN) {
      const ushort* pr = Pp + (size_t)m * 10000 + 5128 + n0 + nl4;
#pragma unroll
      for (int z = 0; z < 8; ++z) {
        ushort4 u = *(const ushort4*)(pr + z * 512);
        sum.x += bf2f(u.x); sum.y += bf2f(u.y);
        sum.z += bf2f(u.z); sum.w += bf2f(u.w);
      }
      *(float4*)(Yf + (size_t)m * BC + n0 + nl4) = sum;
    }
    if (writeT) {
      const int ml = mi + s * 16;
      Lt[nl4 + 0][ml] = f2bf(sum.x);
      Lt[nl4 + 1][ml] = f2bf(sum.y);
      Lt[nl4 + 2][ml] = f2bf(sum.z);
      Lt[nl4 + 3][ml] = f2bf(sum.w);
    }
  }
  if (writeT) {
    __syncthreads();
#pragma unroll
    for (int i = 0; i < 2; ++i) {
      const int g = tid + i * 256;
      const int nl = g >> 3, gi = g & 7;
      *(uint4*)(Yt + (size_t)(n0 + nl) * KPAD + m0 + gi * 8) =
          *(const uint4*)(&Lt[nl][gi * 8]);
    }
  }
}

// ---------------------------------------------------------------------------
// K8/K9: Cb bf16 [5000][Nc] = emb[5000,64] @ Bp[64,Nc]  (Bp pre-permuted,
// coalesced loads; Aet padded +1 to kill 16-way store conflicts).
// ---------------------------------------------------------------------------
__global__ __launch_bounds__(256) void emb_gemm_bf16_kernel(const float* __restrict__ Ae,
                                                            const float* __restrict__ Bp,
                                                            ushort* __restrict__ C,
                                                            int Nc) {
  __shared__ float Aet[EDIM][33];
  __shared__ __align__(16) float Bs[EDIM][64];
  const int row0 = blockIdx.y * 32, col0 = blockIdx.x * 64;
  const int tid = threadIdx.x;
  for (int i = tid; i < 512; i += 256) {
    const int r = i >> 4, d4 = (i & 15) << 2;
    const int gm = row0 + r;
    float4 v = make_float4(0.f, 0.f, 0.f, 0.f);
    if (gm < NN) v = *(const float4*)(Ae + (size_t)gm * EDIM + d4);
    Aet[d4 + 0][r] = v.x; Aet[d4 + 1][r] = v.y; Aet[d4 + 2][r] = v.z; Aet[d4 + 3][r] = v.w;
  }
  for (int i = tid; i < 1024; i += 256) {
    const int br = i >> 4, bc = (i & 15) << 2;
    *(float4*)&Bs[br][bc] = *(const float4*)(Bp + (size_t)br * Nc + col0 + bc);
  }
  __syncthreads();
  const int ty = tid >> 4, tx = tid & 15;
  float acc[2][4] = {};
#pragma unroll 8
  for (int d = 0; d < EDIM; ++d) {
    const float a0 = Aet[d][ty * 2], a1 = Aet[d][ty * 2 + 1];
    const float4 b4 = *(const float4*)&Bs[d][tx << 2];
    acc[0][0] = fmaf(a0, b4.x, acc[0][0]); acc[0][1] = fmaf(a0, b4.y, acc[0][1]);
    acc[0][2] = fmaf(a0, b4.z, acc[0][2]); acc[0][3] = fmaf(a0, b4.w, acc[0][3]);
    acc[1][0] = fmaf(a1, b4.x, acc[1][0]); acc[1][1] = fmaf(a1, b4.y, acc[1][1]);
    acc[1][2] = fmaf(a1, b4.z, acc[1][2]); acc[1][3] = fmaf(a1, b4.w, acc[1][3]);
  }
#pragma unroll
  for (int r = 0; r < 2; ++r) {
    const int gm = row0 + ty * 2 + r;
    if (gm >= NN) continue;
    ushort4 o4;
    o4.x = f2bf(acc[r][0]); o4.y = f2bf(acc[r][1]);
    o4.z = f2bf(acc[r][2]); o4.w = f2bf(acc[r][3]);
    *(ushort4*)(C + (size_t)gm * Nc + col0 + (tx << 2)) = o4;
  }
}

// ---------------------------------------------------------------------------
// K10: biasN fp32 [5000][64] = emb @ bias_pool (Aet padded).
// ---------------------------------------------------------------------------
__global__ __launch_bounds__(256) void emb_gemm_kernel(const float* __restrict__ Ae,
                                                       const float* __restrict__ Bw,
                                                       float* __restrict__ C,
                                                       int M, int Nc) {
  __shared__ float Aet[EDIM][33];
  __shared__ __align__(16) float Bs[EDIM][64];
  const int row0 = blockIdx.y * 32, col0 = blockIdx.x * 64;
  const int tid = threadIdx.x;
  for (int i = tid; i < 512; i += 256) {
    const int r = i >> 4, d4 = (i & 15) << 2;
    const int gm = row0 + r;
    float4 v = make_float4(0.f, 0.f, 0.f, 0.f);
    if (gm < M) v = *(const float4*)(Ae + (size_t)gm * EDIM + d4);
    Aet[d4 + 0][r] = v.x; Aet[d4 + 1][r] = v.y; Aet[d4 + 2][r] = v.z; Aet[d4 + 3][r] = v.w;
  }
  for (int i = tid; i < 1024; i += 256) {
    const int br = i >> 4, bc = (i & 15) << 2;
    if (bc < Nc) *(float4*)&Bs[br][bc] = *(const float4*)(Bw + (size_t)br * Nc + bc);
  }
  __syncthreads();
  const int ty = tid >> 4, tx = tid & 15;
  float acc[2][4] = {};
#pragma unroll 8
  for (int d = 0; d < EDIM; ++d) {
    const float a0 = Aet[d][ty * 2], a1 = Aet[d][ty * 2 + 1];
    const float4 b4 = *(const float4*)&Bs[d][tx << 2];
    acc[0][0] = fmaf(a0, b4.x, acc[0][0]); acc[0][1] = fmaf(a0, b4.y, acc[0][1]);
    acc[0][2] = fmaf(a0, b4.z, acc[0][2]); acc[0][3] = fmaf(a0, b4.w, acc[0][3]);
    acc[1][0] = fmaf(a1, b4.x, acc[1][0]); acc[1][1] = fmaf(a1, b4.y, acc[1][1]);
    acc[1][2] = fmaf(a1, b4.z, acc[1][2]); acc[1][3] = fmaf(a1, b4.w, acc[1][3]);
  }
#pragma unroll
  for (int r = 0; r < 2; ++r) {
    const int gm = row0 + ty * 2 + r;
    if (gm >= M) continue;
    float4 o;
    o.x = acc[r][0]; o.y = acc[r][1]; o.z = acc[r][2]; o.w = acc[r][3];
    *(float4*)(C + (size_t)gm * Nc + col0 + (tx << 2)) = o;
  }
}

// ---------------------------------------------------------------------------
// K11: xwc[b, n, i] = sum_t T[t] * x_window[b, t, n, i]
// ---------------------------------------------------------------------------
__global__ __launch_bounds__(256) void window_combine_kernel(const float* __restrict__ xw,
                                                             const float* __restrict__ T,
                                                             float* __restrict__ out) {
  const int idx = blockIdx.x * 256 + threadIdx.x;
  if (idx >= BB * NN * 16) return;
  const int b = idx / (NN * 16);
  const int rem = idx - b * (NN * 16);
  float acc = 0.f;
#pragma unroll
  for (int t = 0; t < LAGN; ++t)
    acc = fmaf(T[t], xw[(size_t)(b * LAGN + t) * (NN * 16) + rem], acc);
  out[idx] = acc;
}

// ---------------------------------------------------------------------------
// K12: MFMA fusion. One wave per node: gconv (6 MFMAs) + wconv (2 MFMAs),
// LN via 16-lane butterflies on the C-layout, concat + bias.
// ---------------------------------------------------------------------------
__global__ __launch_bounds__(256) void fuse_mfma_kernel(const float* __restrict__ x,
                                                        const float* __restrict__ Y1f,
                                                        const float* __restrict__ Y2f,
                                                        const ushort* __restrict__ Wt,
                                                        const ushort* __restrict__ wwt,
                                                        const float* __restrict__ biasN,
                                                        const float* __restrict__ xwc,
                                                        const float* __restrict__ ln1w,
                                                        const float* __restrict__ ln1b,
                                                        const float* __restrict__ ln2w,
                                                        const float* __restrict__ ln2b,
                                                        float* __restrict__ out) {
  const int tid = threadIdx.x;
  const int n = blockIdx.x * 4 + (tid >> 6);  // grid 1250*4 = 5000 exact
  const int l = tid & 63, fm = l & 15, kq = l >> 4;
  const short8 ax = cvt8(x + ((size_t)fm * NN + n) * DINC + kq * 8);
  const short8 a1 = cvt8(Y1f + (size_t)n * BC + fm * 32 + kq * 8);
  const short8 a2 = cvt8(Y2f + (size_t)n * BC + fm * 32 + kq * 8);
  short8 aw = {};
  if (kq < 2) aw = cvt8(xwc + ((size_t)fm * NN + n) * 16 + kq * 8);
  const ushort* wn = Wt + (size_t)n * 3072;
  const ushort* wwn = wwt + (size_t)n * 512;
  float4v accG[2] = {}, accW[2] = {};
#pragma unroll
  for (int t = 0; t < 2; ++t) {
    const int ob = (t * 16 + fm) * 96 + kq * 8;
    const short8 b0 = *(const short8*)(wn + ob);
    const short8 b1 = *(const short8*)(wn + ob + 32);
    const short8 b2 = *(const short8*)(wn + ob + 64);
    accG[t] = __builtin_amdgcn_mfma_f32_16x16x32_bf16(ax, b0, accG[t], 0, 0, 0);
    accG[t] = __builtin_amdgcn_mfma_f32_16x16x32_bf16(a1, b1, accG[t], 0, 0, 0);
    accG[t] = __builtin_amdgcn_mfma_f32_16x16x32_bf16(a2, b2, accG[t], 0, 0, 0);
    short8 bw = {};
    if (kq < 2) bw = *(const short8*)(wwn + (t * 16 + fm) * 16 + kq * 8);
    accW[t] = __builtin_amdgcn_mfma_f32_16x16x32_bf16(aw, bw, accW[t], 0, 0, 0);
  }
  const float w1a = ln1w[fm], w1b = ln1w[16 + fm];
  const float c1a = ln1b[fm], c1b = ln1b[16 + fm];
  const float w2a = ln2w[fm], w2b = ln2w[16 + fm];
  const float c2a = ln2b[fm], c2b = ln2b[16 + fm];
  const float* bn = biasN + (size_t)n * 64;
  const float bga = bn[fm], bgb = bn[16 + fm];
  const float bwa = bn[32 + fm], bwb = bn[48 + fm];
#pragma unroll
  for (int r = 0; r < 4; ++r) {
    const int b = kq * 4 + r;
    const float g0 = accG[0][r], g1 = accG[1][r];
    float s1 = g0 + g1, s2 = g0 * g0 + g1 * g1;
#pragma unroll
    for (int m = 1; m < 16; m <<= 1) { s1 += __shfl_xor(s1, m); s2 += __shfl_xor(s2, m); }
    const float mu = s1 * 0.03125f;
    const float rs = rsqrtf(s2 * 0.03125f - mu * mu + 1e-5f);
    const float h0 = accW[0][r], h1 = accW[1][r];
    float t1 = h0 + h1, t2 = h0 * h0 + h1 * h1;
#pragma unroll
    for (int m = 1; m < 16; m <<= 1) { t1 += __shfl_xor(t1, m); t2 += __shfl_xor(t2, m); }
    const float mu2 = t1 * 0.03125f;
    const float rs2 = rsqrtf(t2 * 0.03125f - mu2 * mu2 + 1e-5f);
    float* op = out + ((size_t)b * NN + n) * 64;
    op[fm]      = (g0 - mu) * rs * w1a + c1a + bga;
    op[16 + fm] = (g1 - mu) * rs * w1b + c1b + bgb;
    op[32 + fm] = (h0 - mu2) * rs2 * w2a + c2a + bwa;
    op[48 + fm] = (h1 - mu2) * rs2 * w2b + c2b + bwb;
  }
}

// ---------------------------------------------------------------------------
// Workspace map (fp32 slots), high-water 30,410,816 floats = 121.6 MB:
//   [0, 25M)              A fp32 -> P bf16 (row = 10000 ushorts: [0,5120) P+pad,
//                         [5128,9224) 8 bf16 split-K partial slabs)
//                         -> after reduce2: overlaid by Wt/wwt/biasN/xwc
//   [25.0M, 26.31072M)    XbT bf16 [512][5120]   (dead after GEMM1)
//   [26.31072M,27.62144M) Y1t bf16 [512][5120]   (dead after GEMM2)
//   [25.0M, 27.56M)       Y2f fp32 (reduce2 output, overlays XbT+Y1t)
//   [27.62144M,30.18144M) Y1f fp32
//   [30.18144M,30.378048M) wpP fp32 [64][3072] (permuted wpool)
//   [30.378048M,30.410816M) wwP fp32 [64][512] (permuted wwin)
// ---------------------------------------------------------------------------
extern "C" void kernel_launch(void* const* d_in, const int* in_sizes, int n_in,
                              void* d_out, int out_size, void* d_ws, size_t ws_size,
                              hipStream_t stream) {
  const float* x     = (const float*)d_in[0];
  const float* xwin  = (const float*)d_in[1];
  const float* emb   = (const float*)d_in[2];
  const float* wpool = (const float*)d_in[3];
  const float* wwin  = (const float*)d_in[4];
  const float* bpool = (const float*)d_in[5];
  const float* T     = (const float*)d_in[6];
  const float* ln1w  = (const float*)d_in[7];
  const float* ln1b  = (const float*)d_in[8];
  const float* ln2w  = (const float*)d_in[9];
  const float* ln2b  = (const float*)d_in[10];
  float* out = (float*)d_out;
  float* ws = (float*)d_ws;

  float*  A    = ws;
  ushort* P    = (ushort*)ws;
  ushort* XbT  = (ushort*)(ws + 25000000);
  ushort* Y1t  = (ushort*)(ws + 26310720);
  float*  Y1f  = ws + 27621440;
  float*  Y2f  = ws + 25000000;        // overlays XbT+Y1t after GEMM2
  ushort* Wt    = (ushort*)ws;         // [5000][3072] bf16, overlays P after reduce2
  ushort* wwt   = (ushort*)(ws + 15360000);  // [5000][512] bf16
  float*  biasN = ws + 17920000;
  float*  xwc   = ws + 18240000;
  float*  wpP   = ws + 30181440;       // [64][3072]
  float*  wwP   = ws + 30378048;       // [64][512]

  perm_wpool_kernel<<<(64 * 3072 + 255) / 256, 256, 0, stream>>>(wpool, wpP);
  perm_wwin_kernel<<<(64 * 512 + 255) / 256, 256, 0, stream>>>(wwin, wwP);
  build_A_kernel<<<dim3(79, 79), dim3(16, 16), 0, stream>>>(emb, A);
  convert_P_kernel<<<NN, 256, 0, stream>>>(A);
  transpose_xb_kernel<<<dim3(20, 512), 256, 0, stream>>>(x, XbT);
  mfma_gemm_kernel<<<dim3(4, 40, 8), 256, 0, stream>>>(P, XbT, P);
  reduce_kernel<<<dim3(8, 80), 256, 0, stream>>>(P, Y1f, Y1t, 1);
  mfma_gemm_kernel<<<dim3(4, 40, 8), 256, 0, stream>>>(P, Y1t, P);
  reduce_kernel<<<dim3(8, 80), 256, 0, stream>>>(P, Y2f, (ushort*)nullptr, 0);
  emb_gemm_bf16_kernel<<<dim3(48, 157), 256, 0, stream>>>(emb, wpP, Wt, 3072);
  emb_gemm_bf16_kernel<<<dim3(8, 157), 256, 0, stream>>>(emb, wwP, wwt, 512);
  emb_gemm_kernel<<<dim3(1, 157), 256, 0, stream>>>(emb, bpool, biasN, NN, 64);
  window_combine_kernel<<<(BB * NN * 16 + 255) / 256, 256, 0, stream>>>(xwin, T, xwc);
  fuse_mfma_kernel<<<1250, 256, 0, stream>>>(x, Y1f, Y2f, Wt, wwt, biasN, xwc,
                                             ln1w, ln1b, ln2w, ln2b, out);
}

// Round 7
// 459.755 us; speedup vs baseline: 1.2027x; 1.0214x over previous
//
#include <hip/hip_runtime.h>
#include <hip/hip_bf16.h>

// Problem constants (reference setup_inputs)
#define NN   5000   // nodes
#define EDIM 64     // embedding dim
#define DINC 32     // DIN
#define BB   16     // batch
#define LAGN 12     // LAG
#define BC   512    // BB*DINC
#define KPAD 5120   // k-extent padded to 128-tile multiple (zeros in [5000,5120))

typedef __attribute__((ext_vector_type(8))) short short8;   // 8 bf16 = 4 VGPRs
typedef __attribute__((ext_vector_type(4))) float float4v;  // MFMA 16x16 C/D

static __device__ __forceinline__ ushort f2bf(float x) {
  __hip_bfloat16 h = __float2bfloat16(x);
  return *reinterpret_cast<ushort*>(&h);
}
static __device__ __forceinline__ float bf2f(ushort u) {
  unsigned int x = ((unsigned int)u) << 16;
  return __uint_as_float(x);
}
static __device__ __forceinline__ short8 cvt8(const float* p) {  // 8 floats -> bf16x8
  const float4 v0 = *(const float4*)p, v1 = *(const float4*)(p + 4);
  short8 r;
  r[0] = (short)f2bf(v0.x); r[1] = (short)f2bf(v0.y);
  r[2] = (short)f2bf(v0.z); r[3] = (short)f2bf(v0.w);
  r[4] = (short)f2bf(v1.x); r[5] = (short)f2bf(v1.y);
  r[6] = (short)f2bf(v1.z); r[7] = (short)f2bf(v1.w);
  return r;
}

// async global->LDS DMA, 16 B per lane; LDS dst is wave-uniform base + lane*16.
static __device__ __forceinline__ void gll16(const ushort* g, ushort* l) {
  __builtin_amdgcn_global_load_lds(
      (const __attribute__((address_space(1))) void*)g,
      (__attribute__((address_space(3))) void*)l, 16, 0, 0);
}

// P row m (bf16) lives at ushort offset m*10000 + (m&1)*16  -> 64B-aligned rows.
// Split-K partial slab z for row m: ushort offset m*10000 + 5160 + z*512.

// ---------------------------------------------------------------------------
// K0: merged prep — transpose_xb | perm_wpool | perm_wwin. (NOTE: xwc is NOT
// computed here: its buffer overlays the A/P region and must be written only
// after reduce2 — that was R6's correctness bug.)
// Grid 11136 blocks x 256 threads, branch on blockIdx (wave-uniform).
// ---------------------------------------------------------------------------
__global__ __launch_bounds__(256) void prep_kernel(const float* __restrict__ x,
                                                   const float* __restrict__ wpool,
                                                   const float* __restrict__ wwin,
                                                   ushort* __restrict__ XbT,
                                                   float* __restrict__ wpP,
                                                   float* __restrict__ wwP) {
  const int b = blockIdx.x, tid = threadIdx.x;
  if (b < 10240) {            // XbT[j][m] = bf16(x[j>>5][m][j&31]), zero pad m>=NN
    const int j = b / 20, m = (b - j * 20) * 256 + tid;
    const int bb = j >> 5, c = j & 31;
    ushort v = 0;
    if (m < NN) v = f2bf(x[((size_t)bb * NN + m) * DINC + c]);
    XbT[(size_t)j * KPAD + m] = v;
  } else if (b < 11008) {     // wpP: (d,kk,i,o) -> col' = o*96+kk*32+i
    const int t = (b - 10240) * 256 + tid;    // 768*256 = 64*3072
    const int d = t / 3072, r = t - d * 3072;
    const int kk = r >> 10, r2 = r & 1023, i = r2 >> 5, o = r2 & 31;
    wpP[(size_t)d * 3072 + o * 96 + kk * 32 + i] = wpool[t];
  } else {                    // wwP: (d,i,o) -> col' = o*16+i
    const int t = (b - 11008) * 256 + tid;    // 128*256 = 64*512
    const int d = t >> 9, r = t & 511, i = r >> 5, o = r & 31;
    wwP[(size_t)d * 512 + o * 16 + i] = wwin[t];
  }
}

// ---------------------------------------------------------------------------
// K1: A = relu(emb @ emb^T), [NN, NN] fp32, row-major stride NN.
// ---------------------------------------------------------------------------
__global__ __launch_bounds__(256) void build_A_kernel(const float* __restrict__ emb,
                                                      float* __restrict__ A) {
  __shared__ float Er[64][EDIM + 1];
  __shared__ float Ec[64][EDIM + 1];
  const int row0 = blockIdx.y * 64, col0 = blockIdx.x * 64;
  const int tid = threadIdx.y * 16 + threadIdx.x;
  for (int i = tid; i < 1024; i += 256) {
    const int r = i >> 4, d4 = (i & 15) << 2;
    const int gr = row0 + r, gc = col0 + r;
    float4 v = make_float4(0.f, 0.f, 0.f, 0.f);
    float4 w = make_float4(0.f, 0.f, 0.f, 0.f);
    if (gr < NN) v = *(const float4*)(emb + gr * EDIM + d4);
    if (gc < NN) w = *(const float4*)(emb + gc * EDIM + d4);
    Er[r][d4 + 0] = v.x; Er[r][d4 + 1] = v.y; Er[r][d4 + 2] = v.z; Er[r][d4 + 3] = v.w;
    Ec[r][d4 + 0] = w.x; Ec[r][d4 + 1] = w.y; Ec[r][d4 + 2] = w.z; Ec[r][d4 + 3] = w.w;
  }
  __syncthreads();
  const int ty = threadIdx.y, tx = threadIdx.x;
  float acc[4][4] = {};
  for (int d = 0; d < EDIM; ++d) {
    float a[4], b[4];
#pragma unroll
    for (int r = 0; r < 4; ++r) a[r] = Er[ty + r * 16][d];
#pragma unroll
    for (int c = 0; c < 4; ++c) b[c] = Ec[tx + c * 16][d];
#pragma unroll
    for (int r = 0; r < 4; ++r)
#pragma unroll
      for (int c = 0; c < 4; ++c) acc[r][c] = fmaf(a[r], b[c], acc[r][c]);
  }
#pragma unroll
  for (int r = 0; r < 4; ++r) {
    const int gr = row0 + ty + r * 16;
    if (gr >= NN) continue;
#pragma unroll
    for (int c = 0; c < 4; ++c) {
      const int gc = col0 + tx + c * 16;
      if (gc < NN) A[(size_t)gr * NN + gc] = fmaxf(acc[r][c], 0.f);
    }
  }
}

// ---------------------------------------------------------------------------
// K2: fused row-softmax -> bf16 P, IN PLACE over A, 64B-aligned rows via the
// (m&1)*16 stagger. Row fully read into LDS before any write -> in-place safe.
// ---------------------------------------------------------------------------
__global__ __launch_bounds__(256) void convert_P_kernel(float* __restrict__ A) {
  const int m = blockIdx.x;
  float* row = A + (size_t)m * NN;
  __shared__ float buf[NN];
  __shared__ float red[256];
  const int tid = threadIdx.x;
  float mx = 0.f;  // relu >= 0, diag > 0
  for (int i = tid; i < 1250; i += 256) {
    float4 v = *(const float4*)(row + i * 4);
    *(float4*)(buf + i * 4) = v;
    mx = fmaxf(mx, fmaxf(fmaxf(v.x, v.y), fmaxf(v.z, v.w)));
  }
  red[tid] = mx; __syncthreads();
  for (int s = 128; s > 0; s >>= 1) {
    if (tid < s) red[tid] = fmaxf(red[tid], red[tid + s]);
    __syncthreads();
  }
  mx = red[0]; __syncthreads();
  float sum = 0.f;
  for (int i = tid; i < 1250; i += 256) {
    float4 v = *(const float4*)(buf + i * 4);
    v.x = __expf(v.x - mx); v.y = __expf(v.y - mx);
    v.z = __expf(v.z - mx); v.w = __expf(v.w - mx);
    *(float4*)(buf + i * 4) = v;
    sum += v.x + v.y + v.z + v.w;
  }
  red[tid] = sum; __syncthreads();
  for (int s = 128; s > 0; s >>= 1) {
    if (tid < s) red[tid] += red[tid + s];
    __syncthreads();
  }
  const float inv = 1.f / red[0];
  ushort* prow = (ushort*)row + (m & 1) * 16;  // 64B-aligned P row
  for (int i = tid; i < 1250; i += 256) {
    float4 v = *(const float4*)(buf + i * 4);
    ushort4 o;
    o.x = f2bf(v.x * inv); o.y = f2bf(v.y * inv);
    o.z = f2bf(v.z * inv); o.w = f2bf(v.w * inv);
    *(ushort4*)(prow + i * 4) = o;
  }
  if (tid < 120) prow[5000 + tid] = 0;  // k-pad zeros
}

// ---------------------------------------------------------------------------
// K3/K5: bf16 MFMA GEMM. BM=BN=128, BK=64, 256 thr = 4 waves (2x2 of 64x64,
// 32 MFMAs/wave/iter). Split-K=8 (k-chunk 640 = 10 iters), grid 1280.
// LDS chunk-major [c=8][row=128][8 bf16], 16 KB/operand (32 KB -> 5 blk/CU).
// Each row's 128 B/iter = two aligned 64B lines (P rows 64B-aligned).
// ---------------------------------------------------------------------------
__global__ __launch_bounds__(256) void mfma_gemm_kernel(const ushort* __restrict__ Pm,
                                                        const ushort* __restrict__ Bt,
                                                        ushort* __restrict__ Pp) {
  __shared__ __align__(16) ushort As[8192];
  __shared__ __align__(16) ushort Bs[8192];
  const int tid = threadIdx.x;
  const int w = tid >> 6, l = tid & 63;
  const int fm = l & 15, kq = l >> 4;
  const int wm = w >> 1, wn = w & 1;
  const int row0 = blockIdx.y * 128, col0 = blockIdx.x * 128;
  const int kbase = blockIdx.z * 640;
  const int ra = tid & 127;      // staging row
  const int c0 = tid >> 7;       // chunk parity 0/1
  const int arow = row0 + ra;
  const ushort* gA = Pm + (size_t)arow * 10000 + (arow & 1) * 16 + kbase + c0 * 8;
  const ushort* gB = Bt + (size_t)(col0 + ra) * KPAD + kbase + c0 * 8;
  ushort* lA = As + tid * 8;
  ushort* lB = Bs + tid * 8;
  float4v acc[4][4] = {};
  for (int kt = 0; kt < 10; ++kt) {
    __syncthreads();  // prior-iter frag reads done before DMA overwrites LDS
    gll16(gA,      lA);
    gll16(gA + 16, lA + 2048);
    gll16(gA + 32, lA + 4096);
    gll16(gA + 48, lA + 6144);
    gll16(gB,      lB);
    gll16(gB + 16, lB + 2048);
    gll16(gB + 32, lB + 4096);
    gll16(gB + 48, lB + 6144);
    __syncthreads();  // vmcnt(0) drained before barrier -> LDS ready
#pragma unroll
    for (int s = 0; s < 2; ++s) {
      const int cb = (s * 4 + kq) * 1024;  // chunk base (ushorts)
      short8 a[4], b[4];
#pragma unroll
      for (int mt = 0; mt < 4; ++mt)
        a[mt] = *(const short8*)(As + cb + (wm * 64 + mt * 16 + fm) * 8);
#pragma unroll
      for (int nt = 0; nt < 4; ++nt)
        b[nt] = *(const short8*)(Bs + cb + (wn * 64 + nt * 16 + fm) * 8);
#pragma unroll
      for (int mt = 0; mt < 4; ++mt)
#pragma unroll
        for (int nt = 0; nt < 4; ++nt)
          acc[mt][nt] = __builtin_amdgcn_mfma_f32_16x16x32_bf16(a[mt], b[nt], acc[mt][nt], 0, 0, 0);
    }
    gA += 64;  // advance 128 B of k
    gB += 64;
  }
  // epilogue: bf16 partials into the P rows' free halves
  const int cb = col0 + wn * 64 + fm;
  const int zoff = 5160 + blockIdx.z * 512;
#pragma unroll
  for (int mt = 0; mt < 4; ++mt)
#pragma unroll
    for (int r = 0; r < 4; ++r) {
      const int gm = row0 + wm * 64 + mt * 16 + kq * 4 + r;
      if (gm < NN) {
        ushort* prow = Pp + (size_t)gm * 10000 + zoff + cb;
#pragma unroll
        for (int nt = 0; nt < 4; ++nt) prow[nt * 16] = f2bf(acc[mt][nt][r]);
      }
    }
}

// ---------------------------------------------------------------------------
// K4/K6: sum 8 bf16 split-K partials -> Yf fp32 [5000][512]; optionally also
// Yt bf16 [512][KPAD] (transposed, zero pad m in [5000,5120)). Grid (8,80).
// ---------------------------------------------------------------------------
__global__ __launch_bounds__(256) void reduce_kernel(const ushort* __restrict__ Pp,
                                                     float* __restrict__ Yf,
                                                     ushort* __restrict__ Yt,
                                                     int writeT) {
  const int m0 = blockIdx.y * 64, n0 = blockIdx.x * 64;
  __shared__ __align__(16) ushort Lt[64][80];  // [n][m]
  const int tid = threadIdx.x;
  const int mi = tid >> 4, nl4 = (tid & 15) << 2;
#pragma unroll
  for (int s = 0; s < 4; ++s) {
    const int m = m0 + mi + s * 16;
    float4 sum = make_float4(0.f, 0.f, 0.f, 0.f);
    if (m < NN) {
      const ushort* pr = Pp + (size_t)m * 10000 + 5160 + n0 + nl4;
#pragma unroll
      for (int z = 0; z < 8; ++z) {
        ushort4 u = *(const ushort4*)(pr + z * 512);
        sum.x += bf2f(u.x); sum.y += bf2f(u.y);
        sum.z += bf2f(u.z); sum.w += bf2f(u.w);
      }
      *(float4*)(Yf + (size_t)m * BC + n0 + nl4) = sum;
    }
    if (writeT) {
      const int ml = mi + s * 16;
      Lt[nl4 + 0][ml] = f2bf(sum.x);
      Lt[nl4 + 1][ml] = f2bf(sum.y);
      Lt[nl4 + 2][ml] = f2bf(sum.z);
      Lt[nl4 + 3][ml] = f2bf(sum.w);
    }
  }
  if (writeT) {
    __syncthreads();
#pragma unroll
    for (int i = 0; i < 2; ++i) {
      const int g = tid + i * 256;
      const int nl = g >> 3, gi = g & 7;
      *(uint4*)(Yt + (size_t)(n0 + nl) * KPAD + m0 + gi * 8) =
          *(const uint4*)(&Lt[nl][gi * 8]);
    }
  }
}

// ---------------------------------------------------------------------------
// K7/K8: Cb bf16 [5000][Nc] = emb[5000,64] @ Bp[64,Nc]  (Bp pre-permuted).
// ---------------------------------------------------------------------------
__global__ __launch_bounds__(256) void emb_gemm_bf16_kernel(const float* __restrict__ Ae,
                                                            const float* __restrict__ Bp,
                                                            ushort* __restrict__ C,
                                                            int Nc) {
  __shared__ float Aet[EDIM][33];
  __shared__ __align__(16) float Bs[EDIM][64];
  const int row0 = blockIdx.y * 32, col0 = blockIdx.x * 64;
  const int tid = threadIdx.x;
  for (int i = tid; i < 512; i += 256) {
    const int r = i >> 4, d4 = (i & 15) << 2;
    const int gm = row0 + r;
    float4 v = make_float4(0.f, 0.f, 0.f, 0.f);
    if (gm < NN) v = *(const float4*)(Ae + (size_t)gm * EDIM + d4);
    Aet[d4 + 0][r] = v.x; Aet[d4 + 1][r] = v.y; Aet[d4 + 2][r] = v.z; Aet[d4 + 3][r] = v.w;
  }
  for (int i = tid; i < 1024; i += 256) {
    const int br = i >> 4, bc = (i & 15) << 2;
    *(float4*)&Bs[br][bc] = *(const float4*)(Bp + (size_t)br * Nc + col0 + bc);
  }
  __syncthreads();
  const int ty = tid >> 4, tx = tid & 15;
  float acc[2][4] = {};
#pragma unroll 8
  for (int d = 0; d < EDIM; ++d) {
    const float a0 = Aet[d][ty * 2], a1 = Aet[d][ty * 2 + 1];
    const float4 b4 = *(const float4*)&Bs[d][tx << 2];
    acc[0][0] = fmaf(a0, b4.x, acc[0][0]); acc[0][1] = fmaf(a0, b4.y, acc[0][1]);
    acc[0][2] = fmaf(a0, b4.z, acc[0][2]); acc[0][3] = fmaf(a0, b4.w, acc[0][3]);
    acc[1][0] = fmaf(a1, b4.x, acc[1][0]); acc[1][1] = fmaf(a1, b4.y, acc[1][1]);
    acc[1][2] = fmaf(a1, b4.z, acc[1][2]); acc[1][3] = fmaf(a1, b4.w, acc[1][3]);
  }
#pragma unroll
  for (int r = 0; r < 2; ++r) {
    const int gm = row0 + ty * 2 + r;
    if (gm >= NN) continue;
    ushort4 o4;
    o4.x = f2bf(acc[r][0]); o4.y = f2bf(acc[r][1]);
    o4.z = f2bf(acc[r][2]); o4.w = f2bf(acc[r][3]);
    *(ushort4*)(C + (size_t)gm * Nc + col0 + (tx << 2)) = o4;
  }
}

// ---------------------------------------------------------------------------
// K9: biasN fp32 [5000][64] = emb @ bias_pool.
// ---------------------------------------------------------------------------
__global__ __launch_bounds__(256) void emb_gemm_kernel(const float* __restrict__ Ae,
                                                       const float* __restrict__ Bw,
                                                       float* __restrict__ C,
                                                       int M, int Nc) {
  __shared__ float Aet[EDIM][33];
  __shared__ __align__(16) float Bs[EDIM][64];
  const int row0 = blockIdx.y * 32, col0 = blockIdx.x * 64;
  const int tid = threadIdx.x;
  for (int i = tid; i < 512; i += 256) {
    const int r = i >> 4, d4 = (i & 15) << 2;
    const int gm = row0 + r;
    float4 v = make_float4(0.f, 0.f, 0.f, 0.f);
    if (gm < M) v = *(const float4*)(Ae + (size_t)gm * EDIM + d4);
    Aet[d4 + 0][r] = v.x; Aet[d4 + 1][r] = v.y; Aet[d4 + 2][r] = v.z; Aet[d4 + 3][r] = v.w;
  }
  for (int i = tid; i < 1024; i += 256) {
    const int br = i >> 4, bc = (i & 15) << 2;
    if (bc < Nc) *(float4*)&Bs[br][bc] = *(const float4*)(Bw + (size_t)br * Nc + bc);
  }
  __syncthreads();
  const int ty = tid >> 4, tx = tid & 15;
  float acc[2][4] = {};
#pragma unroll 8
  for (int d = 0; d < EDIM; ++d) {
    const float a0 = Aet[d][ty * 2], a1 = Aet[d][ty * 2 + 1];
    const float4 b4 = *(const float4*)&Bs[d][tx << 2];
    acc[0][0] = fmaf(a0, b4.x, acc[0][0]); acc[0][1] = fmaf(a0, b4.y, acc[0][1]);
    acc[0][2] = fmaf(a0, b4.z, acc[0][2]); acc[0][3] = fmaf(a0, b4.w, acc[0][3]);
    acc[1][0] = fmaf(a1, b4.x, acc[1][0]); acc[1][1] = fmaf(a1, b4.y, acc[1][1]);
    acc[1][2] = fmaf(a1, b4.z, acc[1][2]); acc[1][3] = fmaf(a1, b4.w, acc[1][3]);
  }
#pragma unroll
  for (int r = 0; r < 2; ++r) {
    const int gm = row0 + ty * 2 + r;
    if (gm >= M) continue;
    float4 o;
    o.x = acc[r][0]; o.y = acc[r][1]; o.z = acc[r][2]; o.w = acc[r][3];
    *(float4*)(C + (size_t)gm * Nc + col0 + (tx << 2)) = o;
  }
}

// ---------------------------------------------------------------------------
// K10: xwc[b, n, i] = sum_t T[t] * x_window[b, t, n, i]
// (launched AFTER reduce2: xwc buffer overlays the dead A/P region)
// ---------------------------------------------------------------------------
__global__ __launch_bounds__(256) void window_combine_kernel(const float* __restrict__ xw,
                                                             const float* __restrict__ T,
                                                             float* __restrict__ out) {
  const int idx = blockIdx.x * 256 + threadIdx.x;
  if (idx >= BB * NN * 16) return;
  const int b = idx / (NN * 16);
  const int rem = idx - b * (NN * 16);
  float acc = 0.f;
#pragma unroll
  for (int t = 0; t < LAGN; ++t)
    acc = fmaf(T[t], xw[(size_t)(b * LAGN + t) * (NN * 16) + rem], acc);
  out[idx] = acc;
}

// ---------------------------------------------------------------------------
// K11: MFMA fusion. One wave per node: gconv (6 MFMAs) + wconv (2 MFMAs),
// LN via 16-lane butterflies on the C-layout, concat + bias.
// ---------------------------------------------------------------------------
__global__ __launch_bounds__(256) void fuse_mfma_kernel(const float* __restrict__ x,
                                                        const float* __restrict__ Y1f,
                                                        const float* __restrict__ Y2f,
                                                        const ushort* __restrict__ Wt,
                                                        const ushort* __restrict__ wwt,
                                                        const float* __restrict__ biasN,
                                                        const float* __restrict__ xwc,
                                                        const float* __restrict__ ln1w,
                                                        const float* __restrict__ ln1b,
                                                        const float* __restrict__ ln2w,
                                                        const float* __restrict__ ln2b,
                                                        float* __restrict__ out) {
  const int tid = threadIdx.x;
  const int n = blockIdx.x * 4 + (tid >> 6);  // grid 1250*4 = 5000 exact
  const int l = tid & 63, fm = l & 15, kq = l >> 4;
  const short8 ax = cvt8(x + ((size_t)fm * NN + n) * DINC + kq * 8);
  const short8 a1 = cvt8(Y1f + (size_t)n * BC + fm * 32 + kq * 8);
  const short8 a2 = cvt8(Y2f + (size_t)n * BC + fm * 32 + kq * 8);
  short8 aw = {};
  if (kq < 2) aw = cvt8(xwc + ((size_t)fm * NN + n) * 16 + kq * 8);
  const ushort* wn = Wt + (size_t)n * 3072;
  const ushort* wwn = wwt + (size_t)n * 512;
  float4v accG[2] = {}, accW[2] = {};
#pragma unroll
  for (int t = 0; t < 2; ++t) {
    const int ob = (t * 16 + fm) * 96 + kq * 8;
    const short8 b0 = *(const short8*)(wn + ob);
    const short8 b1 = *(const short8*)(wn + ob + 32);
    const short8 b2 = *(const short8*)(wn + ob + 64);
    accG[t] = __builtin_amdgcn_mfma_f32_16x16x32_bf16(ax, b0, accG[t], 0, 0, 0);
    accG[t] = __builtin_amdgcn_mfma_f32_16x16x32_bf16(a1, b1, accG[t], 0, 0, 0);
    accG[t] = __builtin_amdgcn_mfma_f32_16x16x32_bf16(a2, b2, accG[t], 0, 0, 0);
    short8 bw = {};
    if (kq < 2) bw = *(const short8*)(wwn + (t * 16 + fm) * 16 + kq * 8);
    accW[t] = __builtin_amdgcn_mfma_f32_16x16x32_bf16(aw, bw, accW[t], 0, 0, 0);
  }
  const float w1a = ln1w[fm], w1b = ln1w[16 + fm];
  const float c1a = ln1b[fm], c1b = ln1b[16 + fm];
  const float w2a = ln2w[fm], w2b = ln2w[16 + fm];
  const float c2a = ln2b[fm], c2b = ln2b[16 + fm];
  const float* bn = biasN + (size_t)n * 64;
  const float bga = bn[fm], bgb = bn[16 + fm];
  const float bwa = bn[32 + fm], bwb = bn[48 + fm];
#pragma unroll
  for (int r = 0; r < 4; ++r) {
    const int b = kq * 4 + r;
    const float g0 = accG[0][r], g1 = accG[1][r];
    float s1 = g0 + g1, s2 = g0 * g0 + g1 * g1;
#pragma unroll
    for (int m = 1; m < 16; m <<= 1) { s1 += __shfl_xor(s1, m); s2 += __shfl_xor(s2, m); }
    const float mu = s1 * 0.03125f;
    const float rs = rsqrtf(s2 * 0.03125f - mu * mu + 1e-5f);
    const float h0 = accW[0][r], h1 = accW[1][r];
    float t1 = h0 + h1, t2 = h0 * h0 + h1 * h1;
#pragma unroll
    for (int m = 1; m < 16; m <<= 1) { t1 += __shfl_xor(t1, m); t2 += __shfl_xor(t2, m); }
    const float mu2 = t1 * 0.03125f;
    const float rs2 = rsqrtf(t2 * 0.03125f - mu2 * mu2 + 1e-5f);
    float* op = out + ((size_t)b * NN + n) * 64;
    op[fm]      = (g0 - mu) * rs * w1a + c1a + bga;
    op[16 + fm] = (g1 - mu) * rs * w1b + c1b + bgb;
    op[32 + fm] = (h0 - mu2) * rs2 * w2a + c2a + bwa;
    op[48 + fm] = (h1 - mu2) * rs2 * w2b + c2b + bwb;
  }
}

// ---------------------------------------------------------------------------
// Workspace map (fp32 slots), high-water 30,410,816 floats = 121.6 MB:
//   [0, 25M)              A fp32 -> P bf16 in place (row m = ushorts
//                         [m*10000+(m&1)*16, +5120) P, [m*10000+5160, +4096)
//                         8 bf16 split-K partial slabs)
//                         -> after reduce2: overlaid by Wt/wwt/biasN/xwc
//   [25.0M, 26.31072M)    XbT bf16 [512][5120]   (dead after GEMM1)
//   [26.31072M,27.62144M) Y1t bf16 [512][5120]   (dead after GEMM2)
//   [25.0M, 27.56M)       Y2f fp32 (reduce2 output, overlays XbT+Y1t)
//   [27.62144M,30.18144M) Y1f fp32
//   [30.18144M,30.378048M) wpP fp32 [64][3072]
//   [30.378048M,30.410816M) wwP fp32 [64][512]
// ---------------------------------------------------------------------------
extern "C" void kernel_launch(void* const* d_in, const int* in_sizes, int n_in,
                              void* d_out, int out_size, void* d_ws, size_t ws_size,
                              hipStream_t stream) {
  const float* x     = (const float*)d_in[0];
  const float* xwin  = (const float*)d_in[1];
  const float* emb   = (const float*)d_in[2];
  const float* wpool = (const float*)d_in[3];
  const float* wwin  = (const float*)d_in[4];
  const float* bpool = (const float*)d_in[5];
  const float* T     = (const float*)d_in[6];
  const float* ln1w  = (const float*)d_in[7];
  const float* ln1b  = (const float*)d_in[8];
  const float* ln2w  = (const float*)d_in[9];
  const float* ln2b  = (const float*)d_in[10];
  float* out = (float*)d_out;
  float* ws = (float*)d_ws;

  float*  A    = ws;
  ushort* P    = (ushort*)ws;
  ushort* XbT  = (ushort*)(ws + 25000000);
  ushort* Y1t  = (ushort*)(ws + 26310720);
  float*  Y1f  = ws + 27621440;
  float*  Y2f  = ws + 25000000;        // overlays XbT+Y1t after GEMM2
  ushort* Wt    = (ushort*)ws;         // [5000][3072] bf16, overlays P after reduce2
  ushort* wwt   = (ushort*)(ws + 15360000);  // [5000][512] bf16
  float*  biasN = ws + 17920000;
  float*  xwc   = ws + 18240000;       // overlays P rows ~3648..3904 — write after reduce2!
  float*  wpP   = ws + 30181440;       // [64][3072]
  float*  wwP   = ws + 30378048;       // [64][512]

  prep_kernel<<<11136, 256, 0, stream>>>(x, wpool, wwin, XbT, wpP, wwP);
  build_A_kernel<<<dim3(79, 79), dim3(16, 16), 0, stream>>>(emb, A);
  convert_P_kernel<<<NN, 256, 0, stream>>>(A);
  mfma_gemm_kernel<<<dim3(4, 40, 8), 256, 0, stream>>>(P, XbT, P);
  reduce_kernel<<<dim3(8, 80), 256, 0, stream>>>(P, Y1f, Y1t, 1);
  mfma_gemm_kernel<<<dim3(4, 40, 8), 256, 0, stream>>>(P, Y1t, P);
  reduce_kernel<<<dim3(8, 80), 256, 0, stream>>>(P, Y2f, (ushort*)nullptr, 0);
  emb_gemm_bf16_kernel<<<dim3(48, 157), 256, 0, stream>>>(emb, wpP, Wt, 3072);
  emb_gemm_bf16_kernel<<<dim3(8, 157), 256, 0, stream>>>(emb, wwP, wwt, 512);
  emb_gemm_kernel<<<dim3(1, 157), 256, 0, stream>>>(emb, bpool, biasN, NN, 64);
  window_combine_kernel<<<(BB * NN * 16 + 255) / 256, 256, 0, stream>>>(xwin, T, xwc);
  fuse_mfma_kernel<<<1250, 256, 0, stream>>>(x, Y1f, Y2f, Wt, wwt, biasN, xwc,
                                             ln1w, ln1b, ln2w, ln2b, out);
}

// Round 8
// 459.544 us; speedup vs baseline: 1.2033x; 1.0005x over previous
//
#include <hip/hip_runtime.h>
#include <hip/hip_bf16.h>

// Problem constants (reference setup_inputs)
#define NN   5000   // nodes
#define EDIM 64     // embedding dim
#define DINC 32     // DIN
#define BB   16     // batch
#define LAGN 12     // LAG
#define BC   512    // BB*DINC
#define KPAD 5120   // k-extent padded to 128-tile multiple (zeros in [5000,5120))

typedef __attribute__((ext_vector_type(8))) short short8;   // 8 bf16 = 4 VGPRs
typedef __attribute__((ext_vector_type(4))) float float4v;  // MFMA 16x16 C/D

static __device__ __forceinline__ ushort f2bf(float x) {
  __hip_bfloat16 h = __float2bfloat16(x);
  return *reinterpret_cast<ushort*>(&h);
}
static __device__ __forceinline__ float bf2f(ushort u) {
  unsigned int x = ((unsigned int)u) << 16;
  return __uint_as_float(x);
}
static __device__ __forceinline__ short8 cvt8(const float* p) {  // 8 floats -> bf16x8
  const float4 v0 = *(const float4*)p, v1 = *(const float4*)(p + 4);
  short8 r;
  r[0] = (short)f2bf(v0.x); r[1] = (short)f2bf(v0.y);
  r[2] = (short)f2bf(v0.z); r[3] = (short)f2bf(v0.w);
  r[4] = (short)f2bf(v1.x); r[5] = (short)f2bf(v1.y);
  r[6] = (short)f2bf(v1.z); r[7] = (short)f2bf(v1.w);
  return r;
}

// async global->LDS DMA, 16 B per lane; LDS dst is wave-uniform base + lane*16.
static __device__ __forceinline__ void gll16(const ushort* g, ushort* l) {
  __builtin_amdgcn_global_load_lds(
      (const __attribute__((address_space(1))) void*)g,
      (__attribute__((address_space(3))) void*)l, 16, 0, 0);
}

// P row m (bf16) lives at ushort offset m*10000 + (m&1)*16  -> 64B-aligned rows.
// Split-K partial slab z for row m: ushort offset m*10000 + 5160 + z*512.

// ---------------------------------------------------------------------------
// K0: merged prep — transpose_xb | perm_wpool | perm_wwin. (xwc NOT here: its
// buffer overlays the A/P region — write only after reduce2; R6's bug.)
// ---------------------------------------------------------------------------
__global__ __launch_bounds__(256) void prep_kernel(const float* __restrict__ x,
                                                   const float* __restrict__ wpool,
                                                   const float* __restrict__ wwin,
                                                   ushort* __restrict__ XbT,
                                                   float* __restrict__ wpP,
                                                   float* __restrict__ wwP) {
  const int b = blockIdx.x, tid = threadIdx.x;
  if (b < 10240) {            // XbT[j][m] = bf16(x[j>>5][m][j&31]), zero pad m>=NN
    const int j = b / 20, m = (b - j * 20) * 256 + tid;
    const int bb = j >> 5, c = j & 31;
    ushort v = 0;
    if (m < NN) v = f2bf(x[((size_t)bb * NN + m) * DINC + c]);
    XbT[(size_t)j * KPAD + m] = v;
  } else if (b < 11008) {     // wpP: (d,kk,i,o) -> col' = o*96+kk*32+i
    const int t = (b - 10240) * 256 + tid;    // 768*256 = 64*3072
    const int d = t / 3072, r = t - d * 3072;
    const int kk = r >> 10, r2 = r & 1023, i = r2 >> 5, o = r2 & 31;
    wpP[(size_t)d * 3072 + o * 96 + kk * 32 + i] = wpool[t];
  } else {                    // wwP: (d,i,o) -> col' = o*16+i
    const int t = (b - 11008) * 256 + tid;    // 128*256 = 64*512
    const int d = t >> 9, r = t & 511, i = r >> 5, o = r & 31;
    wwP[(size_t)d * 512 + o * 16 + i] = wwin[t];
  }
}

// ---------------------------------------------------------------------------
// K1: A = relu(emb @ emb^T), [NN, NN] fp32, row-major stride NN.
// ---------------------------------------------------------------------------
__global__ __launch_bounds__(256) void build_A_kernel(const float* __restrict__ emb,
                                                      float* __restrict__ A) {
  __shared__ float Er[64][EDIM + 1];
  __shared__ float Ec[64][EDIM + 1];
  const int row0 = blockIdx.y * 64, col0 = blockIdx.x * 64;
  const int tid = threadIdx.y * 16 + threadIdx.x;
  for (int i = tid; i < 1024; i += 256) {
    const int r = i >> 4, d4 = (i & 15) << 2;
    const int gr = row0 + r, gc = col0 + r;
    float4 v = make_float4(0.f, 0.f, 0.f, 0.f);
    float4 w = make_float4(0.f, 0.f, 0.f, 0.f);
    if (gr < NN) v = *(const float4*)(emb + gr * EDIM + d4);
    if (gc < NN) w = *(const float4*)(emb + gc * EDIM + d4);
    Er[r][d4 + 0] = v.x; Er[r][d4 + 1] = v.y; Er[r][d4 + 2] = v.z; Er[r][d4 + 3] = v.w;
    Ec[r][d4 + 0] = w.x; Ec[r][d4 + 1] = w.y; Ec[r][d4 + 2] = w.z; Ec[r][d4 + 3] = w.w;
  }
  __syncthreads();
  const int ty = threadIdx.y, tx = threadIdx.x;
  float acc[4][4] = {};
  for (int d = 0; d < EDIM; ++d) {
    float a[4], b[4];
#pragma unroll
    for (int r = 0; r < 4; ++r) a[r] = Er[ty + r * 16][d];
#pragma unroll
    for (int c = 0; c < 4; ++c) b[c] = Ec[tx + c * 16][d];
#pragma unroll
    for (int r = 0; r < 4; ++r)
#pragma unroll
      for (int c = 0; c < 4; ++c) acc[r][c] = fmaf(a[r], b[c], acc[r][c]);
  }
#pragma unroll
  for (int r = 0; r < 4; ++r) {
    const int gr = row0 + ty + r * 16;
    if (gr >= NN) continue;
#pragma unroll
    for (int c = 0; c < 4; ++c) {
      const int gc = col0 + tx + c * 16;
      if (gc < NN) A[(size_t)gr * NN + gc] = fmaxf(acc[r][c], 0.f);
    }
  }
}

// ---------------------------------------------------------------------------
// K2: fused row-softmax -> bf16 P, IN PLACE over A, 64B-aligned rows via the
// (m&1)*16 stagger. Row fully read into LDS before any write -> in-place safe.
// ---------------------------------------------------------------------------
__global__ __launch_bounds__(256) void convert_P_kernel(float* __restrict__ A) {
  const int m = blockIdx.x;
  float* row = A + (size_t)m * NN;
  __shared__ float buf[NN];
  __shared__ float red[256];
  const int tid = threadIdx.x;
  float mx = 0.f;  // relu >= 0, diag > 0
  for (int i = tid; i < 1250; i += 256) {
    float4 v = *(const float4*)(row + i * 4);
    *(float4*)(buf + i * 4) = v;
    mx = fmaxf(mx, fmaxf(fmaxf(v.x, v.y), fmaxf(v.z, v.w)));
  }
  red[tid] = mx; __syncthreads();
  for (int s = 128; s > 0; s >>= 1) {
    if (tid < s) red[tid] = fmaxf(red[tid], red[tid + s]);
    __syncthreads();
  }
  mx = red[0]; __syncthreads();
  float sum = 0.f;
  for (int i = tid; i < 1250; i += 256) {
    float4 v = *(const float4*)(buf + i * 4);
    v.x = __expf(v.x - mx); v.y = __expf(v.y - mx);
    v.z = __expf(v.z - mx); v.w = __expf(v.w - mx);
    *(float4*)(buf + i * 4) = v;
    sum += v.x + v.y + v.z + v.w;
  }
  red[tid] = sum; __syncthreads();
  for (int s = 128; s > 0; s >>= 1) {
    if (tid < s) red[tid] += red[tid + s];
    __syncthreads();
  }
  const float inv = 1.f / red[0];
  ushort* prow = (ushort*)row + (m & 1) * 16;  // 64B-aligned P row
  for (int i = tid; i < 1250; i += 256) {
    float4 v = *(const float4*)(buf + i * 4);
    ushort4 o;
    o.x = f2bf(v.x * inv); o.y = f2bf(v.y * inv);
    o.z = f2bf(v.z * inv); o.w = f2bf(v.w * inv);
    *(ushort4*)(prow + i * 4) = o;
  }
  if (tid < 120) prow[5000 + tid] = 0;  // k-pad zeros
}

// ---------------------------------------------------------------------------
// K3/K5: bf16 MFMA GEMM. BM=BN=128, BK=64, 256 thr = 4 waves (2x2 of 64x64,
// 32 MFMAs/wave/iter). Split-K=8 (k-chunk 640 = 10 iters), 1D grid 1280 with
// XCD-aware decode: id = x*320 + y*8 + z. The 4 col-tile blocks sharing an
// A-tile (same y,z) have ids 320 apart == same (mod 8) -> same XCD under
// round-robin dispatch -> A-tile fetched from HBM once, shared via that
// XCD's L2. LDS chunk-major [c=8][row=128][8 bf16], conflict-free.
// ---------------------------------------------------------------------------
__global__ __launch_bounds__(256) void mfma_gemm_kernel(const ushort* __restrict__ Pm,
                                                        const ushort* __restrict__ Bt,
                                                        ushort* __restrict__ Pp) {
  __shared__ __align__(16) ushort As[8192];
  __shared__ __align__(16) ushort Bs[8192];
  const int tid = threadIdx.x;
  const int w = tid >> 6, l = tid & 63;
  const int fm = l & 15, kq = l >> 4;
  const int wm = w >> 1, wn = w & 1;
  const int id = blockIdx.x;            // 0..1279
  const int xb = id / 320;              // col tile 0..3
  const int rr = id - xb * 320;
  const int yb = rr >> 3;               // row tile 0..39
  const int zb = rr & 7;                // k-chunk 0..7
  const int row0 = yb * 128, col0 = xb * 128;
  const int kbase = zb * 640;
  const int ra = tid & 127;      // staging row
  const int c0 = tid >> 7;       // chunk parity 0/1
  const int arow = row0 + ra;
  const ushort* gA = Pm + (size_t)arow * 10000 + (arow & 1) * 16 + kbase + c0 * 8;
  const ushort* gB = Bt + (size_t)(col0 + ra) * KPAD + kbase + c0 * 8;
  ushort* lA = As + tid * 8;
  ushort* lB = Bs + tid * 8;
  float4v acc[4][4] = {};
  for (int kt = 0; kt < 10; ++kt) {
    __syncthreads();  // prior-iter frag reads done before DMA overwrites LDS
    gll16(gA,      lA);
    gll16(gA + 16, lA + 2048);
    gll16(gA + 32, lA + 4096);
    gll16(gA + 48, lA + 6144);
    gll16(gB,      lB);
    gll16(gB + 16, lB + 2048);
    gll16(gB + 32, lB + 4096);
    gll16(gB + 48, lB + 6144);
    __syncthreads();  // vmcnt(0) drained before barrier -> LDS ready
#pragma unroll
    for (int s = 0; s < 2; ++s) {
      const int cb = (s * 4 + kq) * 1024;  // chunk base (ushorts)
      short8 a[4], b[4];
#pragma unroll
      for (int mt = 0; mt < 4; ++mt)
        a[mt] = *(const short8*)(As + cb + (wm * 64 + mt * 16 + fm) * 8);
#pragma unroll
      for (int nt = 0; nt < 4; ++nt)
        b[nt] = *(const short8*)(Bs + cb + (wn * 64 + nt * 16 + fm) * 8);
#pragma unroll
      for (int mt = 0; mt < 4; ++mt)
#pragma unroll
        for (int nt = 0; nt < 4; ++nt)
          acc[mt][nt] = __builtin_amdgcn_mfma_f32_16x16x32_bf16(a[mt], b[nt], acc[mt][nt], 0, 0, 0);
    }
    gA += 64;  // advance 128 B of k
    gB += 64;
  }
  // epilogue: bf16 partials into the P rows' free halves
  const int cb = col0 + wn * 64 + fm;
  const int zoff = 5160 + zb * 512;
#pragma unroll
  for (int mt = 0; mt < 4; ++mt)
#pragma unroll
    for (int r = 0; r < 4; ++r) {
      const int gm = row0 + wm * 64 + mt * 16 + kq * 4 + r;
      if (gm < NN) {
        ushort* prow = Pp + (size_t)gm * 10000 + zoff + cb;
#pragma unroll
        for (int nt = 0; nt < 4; ++nt) prow[nt * 16] = f2bf(acc[mt][nt][r]);
      }
    }
}

// ---------------------------------------------------------------------------
// K4/K6: sum 8 bf16 split-K partials -> Yf fp32 [5000][512]; optionally also
// Yt bf16 [512][KPAD] (transposed, zero pad m in [5000,5120)). Grid (8,80).
// ---------------------------------------------------------------------------
__global__ __launch_bounds__(256) void reduce_kernel(const ushort* __restrict__ Pp,
                                                     float* __restrict__ Yf,
                                                     ushort* __restrict__ Yt,
                                                     int writeT) {
  const int m0 = blockIdx.y * 64, n0 = blockIdx.x * 64;
  __shared__ __align__(16) ushort Lt[64][80];  // [n][m]
  const int tid = threadIdx.x;
  const int mi = tid >> 4, nl4 = (tid & 15) << 2;
#pragma unroll
  for (int s = 0; s < 4; ++s) {
    const int m = m0 + mi + s * 16;
    float4 sum = make_float4(0.f, 0.f, 0.f, 0.f);
    if (m < NN) {
      const ushort* pr = Pp + (size_t)m * 10000 + 5160 + n0 + nl4;
#pragma unroll
      for (int z = 0; z < 8; ++z) {
        ushort4 u = *(const ushort4*)(pr + z * 512);
        sum.x += bf2f(u.x); sum.y += bf2f(u.y);
        sum.z += bf2f(u.z); sum.w += bf2f(u.w);
      }
      *(float4*)(Yf + (size_t)m * BC + n0 + nl4) = sum;
    }
    if (writeT) {
      const int ml = mi + s * 16;
      Lt[nl4 + 0][ml] = f2bf(sum.x);
      Lt[nl4 + 1][ml] = f2bf(sum.y);
      Lt[nl4 + 2][ml] = f2bf(sum.z);
      Lt[nl4 + 3][ml] = f2bf(sum.w);
    }
  }
  if (writeT) {
    __syncthreads();
#pragma unroll
    for (int i = 0; i < 2; ++i) {
      const int g = tid + i * 256;
      const int nl = g >> 3, gi = g & 7;
      *(uint4*)(Yt + (size_t)(n0 + nl) * KPAD + m0 + gi * 8) =
          *(const uint4*)(&Lt[nl][gi * 8]);
    }
  }
}

// ---------------------------------------------------------------------------
// K7/K8: Cb bf16 [5000][Nc] = emb[5000,64] @ Bp[64,Nc]  (Bp pre-permuted).
// ---------------------------------------------------------------------------
__global__ __launch_bounds__(256) void emb_gemm_bf16_kernel(const float* __restrict__ Ae,
                                                            const float* __restrict__ Bp,
                                                            ushort* __restrict__ C,
                                                            int Nc) {
  __shared__ float Aet[EDIM][33];
  __shared__ __align__(16) float Bs[EDIM][64];
  const int row0 = blockIdx.y * 32, col0 = blockIdx.x * 64;
  const int tid = threadIdx.x;
  for (int i = tid; i < 512; i += 256) {
    const int r = i >> 4, d4 = (i & 15) << 2;
    const int gm = row0 + r;
    float4 v = make_float4(0.f, 0.f, 0.f, 0.f);
    if (gm < NN) v = *(const float4*)(Ae + (size_t)gm * EDIM + d4);
    Aet[d4 + 0][r] = v.x; Aet[d4 + 1][r] = v.y; Aet[d4 + 2][r] = v.z; Aet[d4 + 3][r] = v.w;
  }
  for (int i = tid; i < 1024; i += 256) {
    const int br = i >> 4, bc = (i & 15) << 2;
    *(float4*)&Bs[br][bc] = *(const float4*)(Bp + (size_t)br * Nc + col0 + bc);
  }
  __syncthreads();
  const int ty = tid >> 4, tx = tid & 15;
  float acc[2][4] = {};
#pragma unroll 8
  for (int d = 0; d < EDIM; ++d) {
    const float a0 = Aet[d][ty * 2], a1 = Aet[d][ty * 2 + 1];
    const float4 b4 = *(const float4*)&Bs[d][tx << 2];
    acc[0][0] = fmaf(a0, b4.x, acc[0][0]); acc[0][1] = fmaf(a0, b4.y, acc[0][1]);
    acc[0][2] = fmaf(a0, b4.z, acc[0][2]); acc[0][3] = fmaf(a0, b4.w, acc[0][3]);
    acc[1][0] = fmaf(a1, b4.x, acc[1][0]); acc[1][1] = fmaf(a1, b4.y, acc[1][1]);
    acc[1][2] = fmaf(a1, b4.z, acc[1][2]); acc[1][3] = fmaf(a1, b4.w, acc[1][3]);
  }
#pragma unroll
  for (int r = 0; r < 2; ++r) {
    const int gm = row0 + ty * 2 + r;
    if (gm >= NN) continue;
    ushort4 o4;
    o4.x = f2bf(acc[r][0]); o4.y = f2bf(acc[r][1]);
    o4.z = f2bf(acc[r][2]); o4.w = f2bf(acc[r][3]);
    *(ushort4*)(C + (size_t)gm * Nc + col0 + (tx << 2)) = o4;
  }
}

// ---------------------------------------------------------------------------
// K9: biasN fp32 [5000][64] = emb @ bias_pool.
// ---------------------------------------------------------------------------
__global__ __launch_bounds__(256) void emb_gemm_kernel(const float* __restrict__ Ae,
                                                       const float* __restrict__ Bw,
                                                       float* __restrict__ C,
                                                       int M, int Nc) {
  __shared__ float Aet[EDIM][33];
  __shared__ __align__(16) float Bs[EDIM][64];
  const int row0 = blockIdx.y * 32, col0 = blockIdx.x * 64;
  const int tid = threadIdx.x;
  for (int i = tid; i < 512; i += 256) {
    const int r = i >> 4, d4 = (i & 15) << 2;
    const int gm = row0 + r;
    float4 v = make_float4(0.f, 0.f, 0.f, 0.f);
    if (gm < M) v = *(const float4*)(Ae + (size_t)gm * EDIM + d4);
    Aet[d4 + 0][r] = v.x; Aet[d4 + 1][r] = v.y; Aet[d4 + 2][r] = v.z; Aet[d4 + 3][r] = v.w;
  }
  for (int i = tid; i < 1024; i += 256) {
    const int br = i >> 4, bc = (i & 15) << 2;
    if (bc < Nc) *(float4*)&Bs[br][bc] = *(const float4*)(Bw + (size_t)br * Nc + bc);
  }
  __syncthreads();
  const int ty = tid >> 4, tx = tid & 15;
  float acc[2][4] = {};
#pragma unroll 8
  for (int d = 0; d < EDIM; ++d) {
    const float a0 = Aet[d][ty * 2], a1 = Aet[d][ty * 2 + 1];
    const float4 b4 = *(const float4*)&Bs[d][tx << 2];
    acc[0][0] = fmaf(a0, b4.x, acc[0][0]); acc[0][1] = fmaf(a0, b4.y, acc[0][1]);
    acc[0][2] = fmaf(a0, b4.z, acc[0][2]); acc[0][3] = fmaf(a0, b4.w, acc[0][3]);
    acc[1][0] = fmaf(a1, b4.x, acc[1][0]); acc[1][1] = fmaf(a1, b4.y, acc[1][1]);
    acc[1][2] = fmaf(a1, b4.z, acc[1][2]); acc[1][3] = fmaf(a1, b4.w, acc[1][3]);
  }
#pragma unroll
  for (int r = 0; r < 2; ++r) {
    const int gm = row0 + ty * 2 + r;
    if (gm >= M) continue;
    float4 o;
    o.x = acc[r][0]; o.y = acc[r][1]; o.z = acc[r][2]; o.w = acc[r][3];
    *(float4*)(C + (size_t)gm * Nc + col0 + (tx << 2)) = o;
  }
}

// ---------------------------------------------------------------------------
// K10: xwc[b, n, i] = sum_t T[t] * x_window[b, t, n, i]
// (launched AFTER reduce2: xwc buffer overlays the dead A/P region)
// ---------------------------------------------------------------------------
__global__ __launch_bounds__(256) void window_combine_kernel(const float* __restrict__ xw,
                                                             const float* __restrict__ T,
                                                             float* __restrict__ out) {
  const int idx = blockIdx.x * 256 + threadIdx.x;
  if (idx >= BB * NN * 16) return;
  const int b = idx / (NN * 16);
  const int rem = idx - b * (NN * 16);
  float acc = 0.f;
#pragma unroll
  for (int t = 0; t < LAGN; ++t)
    acc = fmaf(T[t], xw[(size_t)(b * LAGN + t) * (NN * 16) + rem], acc);
  out[idx] = acc;
}

// ---------------------------------------------------------------------------
// K11: MFMA fusion. One wave per node: gconv (6 MFMAs) + wconv (2 MFMAs),
// LN via 16-lane butterflies on the C-layout, concat + bias.
// ---------------------------------------------------------------------------
__global__ __launch_bounds__(256) void fuse_mfma_kernel(const float* __restrict__ x,
                                                        const float* __restrict__ Y1f,
                                                        const float* __restrict__ Y2f,
                                                        const ushort* __restrict__ Wt,
                                                        const ushort* __restrict__ wwt,
                                                        const float* __restrict__ biasN,
                                                        const float* __restrict__ xwc,
                                                        const float* __restrict__ ln1w,
                                                        const float* __restrict__ ln1b,
                                                        const float* __restrict__ ln2w,
                                                        const float* __restrict__ ln2b,
                                                        float* __restrict__ out) {
  const int tid = threadIdx.x;
  const int n = blockIdx.x * 4 + (tid >> 6);  // grid 1250*4 = 5000 exact
  const int l = tid & 63, fm = l & 15, kq = l >> 4;
  const short8 ax = cvt8(x + ((size_t)fm * NN + n) * DINC + kq * 8);
  const short8 a1 = cvt8(Y1f + (size_t)n * BC + fm * 32 + kq * 8);
  const short8 a2 = cvt8(Y2f + (size_t)n * BC + fm * 32 + kq * 8);
  short8 aw = {};
  if (kq < 2) aw = cvt8(xwc + ((size_t)fm * NN + n) * 16 + kq * 8);
  const ushort* wn = Wt + (size_t)n * 3072;
  const ushort* wwn = wwt + (size_t)n * 512;
  float4v accG[2] = {}, accW[2] = {};
#pragma unroll
  for (int t = 0; t < 2; ++t) {
    const int ob = (t * 16 + fm) * 96 + kq * 8;
    const short8 b0 = *(const short8*)(wn + ob);
    const short8 b1 = *(const short8*)(wn + ob + 32);
    const short8 b2 = *(const short8*)(wn + ob + 64);
    accG[t] = __builtin_amdgcn_mfma_f32_16x16x32_bf16(ax, b0, accG[t], 0, 0, 0);
    accG[t] = __builtin_amdgcn_mfma_f32_16x16x32_bf16(a1, b1, accG[t], 0, 0, 0);
    accG[t] = __builtin_amdgcn_mfma_f32_16x16x32_bf16(a2, b2, accG[t], 0, 0, 0);
    short8 bw = {};
    if (kq < 2) bw = *(const short8*)(wwn + (t * 16 + fm) * 16 + kq * 8);
    accW[t] = __builtin_amdgcn_mfma_f32_16x16x32_bf16(aw, bw, accW[t], 0, 0, 0);
  }
  const float w1a = ln1w[fm], w1b = ln1w[16 + fm];
  const float c1a = ln1b[fm], c1b = ln1b[16 + fm];
  const float w2a = ln2w[fm], w2b = ln2w[16 + fm];
  const float c2a = ln2b[fm], c2b = ln2b[16 + fm];
  const float* bn = biasN + (size_t)n * 64;
  const float bga = bn[fm], bgb = bn[16 + fm];
  const float bwa = bn[32 + fm], bwb = bn[48 + fm];
#pragma unroll
  for (int r = 0; r < 4; ++r) {
    const int b = kq * 4 + r;
    const float g0 = accG[0][r], g1 = accG[1][r];
    float s1 = g0 + g1, s2 = g0 * g0 + g1 * g1;
#pragma unroll
    for (int m = 1; m < 16; m <<= 1) { s1 += __shfl_xor(s1, m); s2 += __shfl_xor(s2, m); }
    const float mu = s1 * 0.03125f;
    const float rs = rsqrtf(s2 * 0.03125f - mu * mu + 1e-5f);
    const float h0 = accW[0][r], h1 = accW[1][r];
    float t1 = h0 + h1, t2 = h0 * h0 + h1 * h1;
#pragma unroll
    for (int m = 1; m < 16; m <<= 1) { t1 += __shfl_xor(t1, m); t2 += __shfl_xor(t2, m); }
    const float mu2 = t1 * 0.03125f;
    const float rs2 = rsqrtf(t2 * 0.03125f - mu2 * mu2 + 1e-5f);
    float* op = out + ((size_t)b * NN + n) * 64;
    op[fm]      = (g0 - mu) * rs * w1a + c1a + bga;
    op[16 + fm] = (g1 - mu) * rs * w1b + c1b + bgb;
    op[32 + fm] = (h0 - mu2) * rs2 * w2a + c2a + bwa;
    op[48 + fm] = (h1 - mu2) * rs2 * w2b + c2b + bwb;
  }
}

// ---------------------------------------------------------------------------
// Workspace map (fp32 slots), high-water 30,410,816 floats = 121.6 MB:
//   [0, 25M)              A fp32 -> P bf16 in place (row m = ushorts
//                         [m*10000+(m&1)*16, +5120) P, [m*10000+5160, +4096)
//                         8 bf16 split-K partial slabs)
//                         -> after reduce2: overlaid by Wt/wwt/biasN/xwc
//   [25.0M, 26.31072M)    XbT bf16 [512][5120]   (dead after GEMM1)
//   [26.31072M,27.62144M) Y1t bf16 [512][5120]   (dead after GEMM2)
//   [25.0M, 27.56M)       Y2f fp32 (reduce2 output, overlays XbT+Y1t)
//   [27.62144M,30.18144M) Y1f fp32
//   [30.18144M,30.378048M) wpP fp32 [64][3072]
//   [30.378048M,30.410816M) wwP fp32 [64][512]
// ---------------------------------------------------------------------------
extern "C" void kernel_launch(void* const* d_in, const int* in_sizes, int n_in,
                              void* d_out, int out_size, void* d_ws, size_t ws_size,
                              hipStream_t stream) {
  const float* x     = (const float*)d_in[0];
  const float* xwin  = (const float*)d_in[1];
  const float* emb   = (const float*)d_in[2];
  const float* wpool = (const float*)d_in[3];
  const float* wwin  = (const float*)d_in[4];
  const float* bpool = (const float*)d_in[5];
  const float* T     = (const float*)d_in[6];
  const float* ln1w  = (const float*)d_in[7];
  const float* ln1b  = (const float*)d_in[8];
  const float* ln2w  = (const float*)d_in[9];
  const float* ln2b  = (const float*)d_in[10];
  float* out = (float*)d_out;
  float* ws = (float*)d_ws;

  float*  A    = ws;
  ushort* P    = (ushort*)ws;
  ushort* XbT  = (ushort*)(ws + 25000000);
  ushort* Y1t  = (ushort*)(ws + 26310720);
  float*  Y1f  = ws + 27621440;
  float*  Y2f  = ws + 25000000;        // overlays XbT+Y1t after GEMM2
  ushort* Wt    = (ushort*)ws;         // [5000][3072] bf16, overlays P after reduce2
  ushort* wwt   = (ushort*)(ws + 15360000);  // [5000][512] bf16
  float*  biasN = ws + 17920000;
  float*  xwc   = ws + 18240000;       // overlays P rows — write after reduce2!
  float*  wpP   = ws + 30181440;       // [64][3072]
  float*  wwP   = ws + 30378048;       // [64][512]

  prep_kernel<<<11136, 256, 0, stream>>>(x, wpool, wwin, XbT, wpP, wwP);
  build_A_kernel<<<dim3(79, 79), dim3(16, 16), 0, stream>>>(emb, A);
  convert_P_kernel<<<NN, 256, 0, stream>>>(A);
  mfma_gemm_kernel<<<1280, 256, 0, stream>>>(P, XbT, P);
  reduce_kernel<<<dim3(8, 80), 256, 0, stream>>>(P, Y1f, Y1t, 1);
  mfma_gemm_kernel<<<1280, 256, 0, stream>>>(P, Y1t, P);
  reduce_kernel<<<dim3(8, 80), 256, 0, stream>>>(P, Y2f, (ushort*)nullptr, 0);
  emb_gemm_bf16_kernel<<<dim3(48, 157), 256, 0, stream>>>(emb, wpP, Wt, 3072);
  emb_gemm_bf16_kernel<<<dim3(8, 157), 256, 0, stream>>>(emb, wwP, wwt, 512);
  emb_gemm_kernel<<<dim3(1, 157), 256, 0, stream>>>(emb, bpool, biasN, NN, 64);
  window_combine_kernel<<<(BB * NN * 16 + 255) / 256, 256, 0, stream>>>(xwin, T, xwc);
  fuse_mfma_kernel<<<1250, 256, 0, stream>>>(x, Y1f, Y2f, Wt, wwt, biasN, xwc,
                                             ln1w, ln1b, ln2w, ln2b, out);
}

// Round 9
// 428.871 us; speedup vs baseline: 1.2893x; 1.0715x over previous
//
#include <hip/hip_runtime.h>
#include <hip/hip_bf16.h>

// Problem constants (reference setup_inputs)
#define NN   5000   // nodes
#define EDIM 64     // embedding dim
#define DINC 32     // DIN
#define BB   16     // batch
#define LAGN 12     // LAG
#define BC   512    // BB*DINC
#define KPAD 5120   // k-extent padded to 128-tile multiple (zeros in [5000,5120))

typedef __attribute__((ext_vector_type(8))) short short8;   // 8 bf16 = 4 VGPRs
typedef __attribute__((ext_vector_type(4))) float float4v;  // MFMA 16x16 C/D

static __device__ __forceinline__ ushort f2bf(float x) {
  __hip_bfloat16 h = __float2bfloat16(x);
  return *reinterpret_cast<ushort*>(&h);
}
static __device__ __forceinline__ float bf2f(ushort u) {
  unsigned int x = ((unsigned int)u) << 16;
  return __uint_as_float(x);
}
static __device__ __forceinline__ short8 cvt8(const float* p) {  // 8 floats -> bf16x8
  const float4 v0 = *(const float4*)p, v1 = *(const float4*)(p + 4);
  short8 r;
  r[0] = (short)f2bf(v0.x); r[1] = (short)f2bf(v0.y);
  r[2] = (short)f2bf(v0.z); r[3] = (short)f2bf(v0.w);
  r[4] = (short)f2bf(v1.x); r[5] = (short)f2bf(v1.y);
  r[6] = (short)f2bf(v1.z); r[7] = (short)f2bf(v1.w);
  return r;
}

// async global->LDS DMA, 16 B per lane; LDS dst is wave-uniform base + lane*16.
static __device__ __forceinline__ void gll16(const ushort* g, ushort* l) {
  __builtin_amdgcn_global_load_lds(
      (const __attribute__((address_space(1))) void*)g,
      (__attribute__((address_space(3))) void*)l, 16, 0, 0);
}

// P row m (bf16) lives at ushort offset m*10000 + (m&1)*16  -> 64B-aligned rows.
// Split-K partial slab z for row m: ushort offset m*10000 + 5160 + z*512.

// ---------------------------------------------------------------------------
// K0: merged prep — transpose_xb | perm_wpool | perm_wwin. (xwc NOT here: its
// buffer overlays the A/P region — write only after reduce2; R6's bug.)
// ---------------------------------------------------------------------------
__global__ __launch_bounds__(256) void prep_kernel(const float* __restrict__ x,
                                                   const float* __restrict__ wpool,
                                                   const float* __restrict__ wwin,
                                                   ushort* __restrict__ XbT,
                                                   float* __restrict__ wpP,
                                                   float* __restrict__ wwP) {
  const int b = blockIdx.x, tid = threadIdx.x;
  if (b < 10240) {            // XbT[j][m] = bf16(x[j>>5][m][j&31]), zero pad m>=NN
    const int j = b / 20, m = (b - j * 20) * 256 + tid;
    const int bb = j >> 5, c = j & 31;
    ushort v = 0;
    if (m < NN) v = f2bf(x[((size_t)bb * NN + m) * DINC + c]);
    XbT[(size_t)j * KPAD + m] = v;
  } else if (b < 11008) {     // wpP: (d,kk,i,o) -> col' = o*96+kk*32+i
    const int t = (b - 10240) * 256 + tid;    // 768*256 = 64*3072
    const int d = t / 3072, r = t - d * 3072;
    const int kk = r >> 10, r2 = r & 1023, i = r2 >> 5, o = r2 & 31;
    wpP[(size_t)d * 3072 + o * 96 + kk * 32 + i] = wpool[t];
  } else {                    // wwP: (d,i,o) -> col' = o*16+i
    const int t = (b - 11008) * 256 + tid;    // 128*256 = 64*512
    const int d = t >> 9, r = t & 511, i = r >> 5, o = r & 31;
    wwP[(size_t)d * 512 + o * 16 + i] = wwin[t];
  }
}

// ---------------------------------------------------------------------------
// K1: A = relu(emb @ emb^T), [NN, NN] fp32, row-major stride NN.
// ---------------------------------------------------------------------------
__global__ __launch_bounds__(256) void build_A_kernel(const float* __restrict__ emb,
                                                      float* __restrict__ A) {
  __shared__ float Er[64][EDIM + 1];
  __shared__ float Ec[64][EDIM + 1];
  const int row0 = blockIdx.y * 64, col0 = blockIdx.x * 64;
  const int tid = threadIdx.y * 16 + threadIdx.x;
  for (int i = tid; i < 1024; i += 256) {
    const int r = i >> 4, d4 = (i & 15) << 2;
    const int gr = row0 + r, gc = col0 + r;
    float4 v = make_float4(0.f, 0.f, 0.f, 0.f);
    float4 w = make_float4(0.f, 0.f, 0.f, 0.f);
    if (gr < NN) v = *(const float4*)(emb + gr * EDIM + d4);
    if (gc < NN) w = *(const float4*)(emb + gc * EDIM + d4);
    Er[r][d4 + 0] = v.x; Er[r][d4 + 1] = v.y; Er[r][d4 + 2] = v.z; Er[r][d4 + 3] = v.w;
    Ec[r][d4 + 0] = w.x; Ec[r][d4 + 1] = w.y; Ec[r][d4 + 2] = w.z; Ec[r][d4 + 3] = w.w;
  }
  __syncthreads();
  const int ty = threadIdx.y, tx = threadIdx.x;
  float acc[4][4] = {};
  for (int d = 0; d < EDIM; ++d) {
    float a[4], b[4];
#pragma unroll
    for (int r = 0; r < 4; ++r) a[r] = Er[ty + r * 16][d];
#pragma unroll
    for (int c = 0; c < 4; ++c) b[c] = Ec[tx + c * 16][d];
#pragma unroll
    for (int r = 0; r < 4; ++r)
#pragma unroll
      for (int c = 0; c < 4; ++c) acc[r][c] = fmaf(a[r], b[c], acc[r][c]);
  }
#pragma unroll
  for (int r = 0; r < 4; ++r) {
    const int gr = row0 + ty + r * 16;
    if (gr >= NN) continue;
#pragma unroll
    for (int c = 0; c < 4; ++c) {
      const int gc = col0 + tx + c * 16;
      if (gc < NN) A[(size_t)gr * NN + gc] = fmaxf(acc[r][c], 0.f);
    }
  }
}

// ---------------------------------------------------------------------------
// K2: fused row-softmax -> bf16 P, IN PLACE over A, 64B-aligned rows via the
// (m&1)*16 stagger. Row fully read into LDS before any write -> in-place safe.
// ---------------------------------------------------------------------------
__global__ __launch_bounds__(256) void convert_P_kernel(float* __restrict__ A) {
  const int m = blockIdx.x;
  float* row = A + (size_t)m * NN;
  __shared__ float buf[NN];
  __shared__ float red[256];
  const int tid = threadIdx.x;
  float mx = 0.f;  // relu >= 0, diag > 0
  for (int i = tid; i < 1250; i += 256) {
    float4 v = *(const float4*)(row + i * 4);
    *(float4*)(buf + i * 4) = v;
    mx = fmaxf(mx, fmaxf(fmaxf(v.x, v.y), fmaxf(v.z, v.w)));
  }
  red[tid] = mx; __syncthreads();
  for (int s = 128; s > 0; s >>= 1) {
    if (tid < s) red[tid] = fmaxf(red[tid], red[tid + s]);
    __syncthreads();
  }
  mx = red[0]; __syncthreads();
  float sum = 0.f;
  for (int i = tid; i < 1250; i += 256) {
    float4 v = *(const float4*)(buf + i * 4);
    v.x = __expf(v.x - mx); v.y = __expf(v.y - mx);
    v.z = __expf(v.z - mx); v.w = __expf(v.w - mx);
    *(float4*)(buf + i * 4) = v;
    sum += v.x + v.y + v.z + v.w;
  }
  red[tid] = sum; __syncthreads();
  for (int s = 128; s > 0; s >>= 1) {
    if (tid < s) red[tid] += red[tid + s];
    __syncthreads();
  }
  const float inv = 1.f / red[0];
  ushort* prow = (ushort*)row + (m & 1) * 16;  // 64B-aligned P row
  for (int i = tid; i < 1250; i += 256) {
    float4 v = *(const float4*)(buf + i * 4);
    ushort4 o;
    o.x = f2bf(v.x * inv); o.y = f2bf(v.y * inv);
    o.z = f2bf(v.z * inv); o.w = f2bf(v.w * inv);
    *(ushort4*)(prow + i * 4) = o;
  }
  if (tid < 120) prow[5000 + tid] = 0;  // k-pad zeros
}

// ---------------------------------------------------------------------------
// K3/K5: bf16 MFMA GEMM. BM=BN=128, BK=64, 256 thr = 4 waves (2x2 of 64x64,
// 32 MFMAs/wave/iter). Split-K=8 (k-chunk 640 = 10 iters), 1D grid 1280 with
// XCD-aware decode (id = x*320 + y*8 + z: A-tile sharers land on one XCD).
// DMA locality fix (R9): each wave-instruction loads 8 ROWS x 128 B
// (8 lanes/row, 16 B each) instead of 64 rows x 16 B -> 16 sectors/instr
// instead of 64 (4x fewer TA requests). LDS is row-major [128][64] ushorts
// (forced by the DMA lane-order constraint); bank conflicts avoided by a
// GLOBAL-side k-chunk XOR swizzle: lane fetches global chunk (l&7)^(row&7),
// so frag reads address slot (s*4+kq)^(fm&7) -> per quarter-wave a bijection
// over the 8 bank groups (2 lanes/group = free).
// ---------------------------------------------------------------------------
__global__ __launch_bounds__(256) void mfma_gemm_kernel(const ushort* __restrict__ Pm,
                                                        const ushort* __restrict__ Bt,
                                                        ushort* __restrict__ Pp) {
  __shared__ __align__(16) ushort As[8192];  // row-major [128][64]
  __shared__ __align__(16) ushort Bs[8192];
  const int tid = threadIdx.x;
  const int w = tid >> 6, l = tid & 63;
  const int fm = l & 15, kq = l >> 4;
  const int wm = w >> 1, wn = w & 1;
  const int id = blockIdx.x;            // 0..1279
  const int xb = id / 320;              // col tile 0..3
  const int rr = id - xb * 320;
  const int yb = rr >> 3;               // row tile 0..39
  const int zb = rr & 7;                // k-chunk 0..7
  const int row0 = yb * 128, col0 = xb * 128;
  const int kbase = zb * 640;
  // staging: call q covers rows q*32+(tid>>3), chunk slot tid&7 (XOR-swizzled)
  const int rstg = tid >> 3;            // 0..31
  const int slot = tid & 7;
  const ushort* gAq[4];
  const ushort* gBq[4];
#pragma unroll
  for (int q = 0; q < 4; ++q) {
    const int r = q * 32 + rstg;
    const int cg = slot ^ (r & 7);      // global k-chunk this lane fetches
    const int arow = row0 + r;
    gAq[q] = Pm + (size_t)arow * 10000 + (arow & 1) * 16 + kbase + cg * 8;
    gBq[q] = Bt + (size_t)(col0 + r) * KPAD + kbase + cg * 8;
  }
  ushort* lA = As + tid * 8;            // call q adds q*2048 (row-major exact)
  ushort* lB = Bs + tid * 8;
  float4v acc[4][4] = {};
  for (int kt = 0; kt < 10; ++kt) {
    __syncthreads();  // prior-iter frag reads done before DMA overwrites LDS
#pragma unroll
    for (int q = 0; q < 4; ++q) gll16(gAq[q], lA + q * 2048);
#pragma unroll
    for (int q = 0; q < 4; ++q) gll16(gBq[q], lB + q * 2048);
    __syncthreads();  // vmcnt(0) drained before barrier -> LDS ready
#pragma unroll
    for (int s = 0; s < 2; ++s) {
      short8 a[4], b[4];
#pragma unroll
      for (int mt = 0; mt < 4; ++mt) {
        const int row = wm * 64 + mt * 16 + fm;
        const int sl = (s * 4 + kq) ^ (fm & 7);
        a[mt] = *(const short8*)(As + row * 64 + sl * 8);
      }
#pragma unroll
      for (int nt = 0; nt < 4; ++nt) {
        const int row = wn * 64 + nt * 16 + fm;
        const int sl = (s * 4 + kq) ^ (fm & 7);
        b[nt] = *(const short8*)(Bs + row * 64 + sl * 8);
      }
#pragma unroll
      for (int mt = 0; mt < 4; ++mt)
#pragma unroll
        for (int nt = 0; nt < 4; ++nt)
          acc[mt][nt] = __builtin_amdgcn_mfma_f32_16x16x32_bf16(a[mt], b[nt], acc[mt][nt], 0, 0, 0);
    }
#pragma unroll
    for (int q = 0; q < 4; ++q) { gAq[q] += 64; gBq[q] += 64; }
  }
  // epilogue: bf16 partials into the P rows' free halves
  const int cb = col0 + wn * 64 + fm;
  const int zoff = 5160 + zb * 512;
#pragma unroll
  for (int mt = 0; mt < 4; ++mt)
#pragma unroll
    for (int r = 0; r < 4; ++r) {
      const int gm = row0 + wm * 64 + mt * 16 + kq * 4 + r;
      if (gm < NN) {
        ushort* prow = Pp + (size_t)gm * 10000 + zoff + cb;
#pragma unroll
        for (int nt = 0; nt < 4; ++nt) prow[nt * 16] = f2bf(acc[mt][nt][r]);
      }
    }
}

// ---------------------------------------------------------------------------
// K4/K6: sum 8 bf16 split-K partials -> Yf fp32 [5000][512]; optionally also
// Yt bf16 [512][KPAD] (transposed, zero pad m in [5000,5120)). Grid (8,80).
// ---------------------------------------------------------------------------
__global__ __launch_bounds__(256) void reduce_kernel(const ushort* __restrict__ Pp,
                                                     float* __restrict__ Yf,
                                                     ushort* __restrict__ Yt,
                                                     int writeT) {
  const int m0 = blockIdx.y * 64, n0 = blockIdx.x * 64;
  __shared__ __align__(16) ushort Lt[64][80];  // [n][m]
  const int tid = threadIdx.x;
  const int mi = tid >> 4, nl4 = (tid & 15) << 2;
#pragma unroll
  for (int s = 0; s < 4; ++s) {
    const int m = m0 + mi + s * 16;
    float4 sum = make_float4(0.f, 0.f, 0.f, 0.f);
    if (m < NN) {
      const ushort* pr = Pp + (size_t)m * 10000 + 5160 + n0 + nl4;
#pragma unroll
      for (int z = 0; z < 8; ++z) {
        ushort4 u = *(const ushort4*)(pr + z * 512);
        sum.x += bf2f(u.x); sum.y += bf2f(u.y);
        sum.z += bf2f(u.z); sum.w += bf2f(u.w);
      }
      *(float4*)(Yf + (size_t)m * BC + n0 + nl4) = sum;
    }
    if (writeT) {
      const int ml = mi + s * 16;
      Lt[nl4 + 0][ml] = f2bf(sum.x);
      Lt[nl4 + 1][ml] = f2bf(sum.y);
      Lt[nl4 + 2][ml] = f2bf(sum.z);
      Lt[nl4 + 3][ml] = f2bf(sum.w);
    }
  }
  if (writeT) {
    __syncthreads();
#pragma unroll
    for (int i = 0; i < 2; ++i) {
      const int g = tid + i * 256;
      const int nl = g >> 3, gi = g & 7;
      *(uint4*)(Yt + (size_t)(n0 + nl) * KPAD + m0 + gi * 8) =
          *(const uint4*)(&Lt[nl][gi * 8]);
    }
  }
}

// ---------------------------------------------------------------------------
// K7/K8: Cb bf16 [5000][Nc] = emb[5000,64] @ Bp[64,Nc]  (Bp pre-permuted).
// ---------------------------------------------------------------------------
__global__ __launch_bounds__(256) void emb_gemm_bf16_kernel(const float* __restrict__ Ae,
                                                            const float* __restrict__ Bp,
                                                            ushort* __restrict__ C,
                                                            int Nc) {
  __shared__ float Aet[EDIM][33];
  __shared__ __align__(16) float Bs[EDIM][64];
  const int row0 = blockIdx.y * 32, col0 = blockIdx.x * 64;
  const int tid = threadIdx.x;
  for (int i = tid; i < 512; i += 256) {
    const int r = i >> 4, d4 = (i & 15) << 2;
    const int gm = row0 + r;
    float4 v = make_float4(0.f, 0.f, 0.f, 0.f);
    if (gm < NN) v = *(const float4*)(Ae + (size_t)gm * EDIM + d4);
    Aet[d4 + 0][r] = v.x; Aet[d4 + 1][r] = v.y; Aet[d4 + 2][r] = v.z; Aet[d4 + 3][r] = v.w;
  }
  for (int i = tid; i < 1024; i += 256) {
    const int br = i >> 4, bc = (i & 15) << 2;
    *(float4*)&Bs[br][bc] = *(const float4*)(Bp + (size_t)br * Nc + col0 + bc);
  }
  __syncthreads();
  const int ty = tid >> 4, tx = tid & 15;
  float acc[2][4] = {};
#pragma unroll 8
  for (int d = 0; d < EDIM; ++d) {
    const float a0 = Aet[d][ty * 2], a1 = Aet[d][ty * 2 + 1];
    const float4 b4 = *(const float4*)&Bs[d][tx << 2];
    acc[0][0] = fmaf(a0, b4.x, acc[0][0]); acc[0][1] = fmaf(a0, b4.y, acc[0][1]);
    acc[0][2] = fmaf(a0, b4.z, acc[0][2]); acc[0][3] = fmaf(a0, b4.w, acc[0][3]);
    acc[1][0] = fmaf(a1, b4.x, acc[1][0]); acc[1][1] = fmaf(a1, b4.y, acc[1][1]);
    acc[1][2] = fmaf(a1, b4.z, acc[1][2]); acc[1][3] = fmaf(a1, b4.w, acc[1][3]);
  }
#pragma unroll
  for (int r = 0; r < 2; ++r) {
    const int gm = row0 + ty * 2 + r;
    if (gm >= NN) continue;
    ushort4 o4;
    o4.x = f2bf(acc[r][0]); o4.y = f2bf(acc[r][1]);
    o4.z = f2bf(acc[r][2]); o4.w = f2bf(acc[r][3]);
    *(ushort4*)(C + (size_t)gm * Nc + col0 + (tx << 2)) = o4;
  }
}

// ---------------------------------------------------------------------------
// K9: biasN fp32 [5000][64] = emb @ bias_pool.
// ---------------------------------------------------------------------------
__global__ __launch_bounds__(256) void emb_gemm_kernel(const float* __restrict__ Ae,
                                                       const float* __restrict__ Bw,
                                                       float* __restrict__ C,
                                                       int M, int Nc) {
  __shared__ float Aet[EDIM][33];
  __shared__ __align__(16) float Bs[EDIM][64];
  const int row0 = blockIdx.y * 32, col0 = blockIdx.x * 64;
  const int tid = threadIdx.x;
  for (int i = tid; i < 512; i += 256) {
    const int r = i >> 4, d4 = (i & 15) << 2;
    const int gm = row0 + r;
    float4 v = make_float4(0.f, 0.f, 0.f, 0.f);
    if (gm < M) v = *(const float4*)(Ae + (size_t)gm * EDIM + d4);
    Aet[d4 + 0][r] = v.x; Aet[d4 + 1][r] = v.y; Aet[d4 + 2][r] = v.z; Aet[d4 + 3][r] = v.w;
  }
  for (int i = tid; i < 1024; i += 256) {
    const int br = i >> 4, bc = (i & 15) << 2;
    if (bc < Nc) *(float4*)&Bs[br][bc] = *(const float4*)(Bw + (size_t)br * Nc + bc);
  }
  __syncthreads();
  const int ty = tid >> 4, tx = tid & 15;
  float acc[2][4] = {};
#pragma unroll 8
  for (int d = 0; d < EDIM; ++d) {
    const float a0 = Aet[d][ty * 2], a1 = Aet[d][ty * 2 + 1];
    const float4 b4 = *(const float4*)&Bs[d][tx << 2];
    acc[0][0] = fmaf(a0, b4.x, acc[0][0]); acc[0][1] = fmaf(a0, b4.y, acc[0][1]);
    acc[0][2] = fmaf(a0, b4.z, acc[0][2]); acc[0][3] = fmaf(a0, b4.w, acc[0][3]);
    acc[1][0] = fmaf(a1, b4.x, acc[1][0]); acc[1][1] = fmaf(a1, b4.y, acc[1][1]);
    acc[1][2] = fmaf(a1, b4.z, acc[1][2]); acc[1][3] = fmaf(a1, b4.w, acc[1][3]);
  }
#pragma unroll
  for (int r = 0; r < 2; ++r) {
    const int gm = row0 + ty * 2 + r;
    if (gm >= M) continue;
    float4 o;
    o.x = acc[r][0]; o.y = acc[r][1]; o.z = acc[r][2]; o.w = acc[r][3];
    *(float4*)(C + (size_t)gm * Nc + col0 + (tx << 2)) = o;
  }
}

// ---------------------------------------------------------------------------
// K10: xwc[b, n, i] = sum_t T[t] * x_window[b, t, n, i]
// (launched AFTER reduce2: xwc buffer overlays the dead A/P region)
// ---------------------------------------------------------------------------
__global__ __launch_bounds__(256) void window_combine_kernel(const float* __restrict__ xw,
                                                             const float* __restrict__ T,
                                                             float* __restrict__ out) {
  const int idx = blockIdx.x * 256 + threadIdx.x;
  if (idx >= BB * NN * 16) return;
  const int b = idx / (NN * 16);
  const int rem = idx - b * (NN * 16);
  float acc = 0.f;
#pragma unroll
  for (int t = 0; t < LAGN; ++t)
    acc = fmaf(T[t], xw[(size_t)(b * LAGN + t) * (NN * 16) + rem], acc);
  out[idx] = acc;
}

// ---------------------------------------------------------------------------
// K11: MFMA fusion. One wave per node: gconv (6 MFMAs) + wconv (2 MFMAs),
// LN via 16-lane butterflies on the C-layout, concat + bias.
// ---------------------------------------------------------------------------
__global__ __launch_bounds__(256) void fuse_mfma_kernel(const float* __restrict__ x,
                                                        const float* __restrict__ Y1f,
                                                        const float* __restrict__ Y2f,
                                                        const ushort* __restrict__ Wt,
                                                        const ushort* __restrict__ wwt,
                                                        const float* __restrict__ biasN,
                                                        const float* __restrict__ xwc,
                                                        const float* __restrict__ ln1w,
                                                        const float* __restrict__ ln1b,
                                                        const float* __restrict__ ln2w,
                                                        const float* __restrict__ ln2b,
                                                        float* __restrict__ out) {
  const int tid = threadIdx.x;
  const int n = blockIdx.x * 4 + (tid >> 6);  // grid 1250*4 = 5000 exact
  const int l = tid & 63, fm = l & 15, kq = l >> 4;
  const short8 ax = cvt8(x + ((size_t)fm * NN + n) * DINC + kq * 8);
  const short8 a1 = cvt8(Y1f + (size_t)n * BC + fm * 32 + kq * 8);
  const short8 a2 = cvt8(Y2f + (size_t)n * BC + fm * 32 + kq * 8);
  short8 aw = {};
  if (kq < 2) aw = cvt8(xwc + ((size_t)fm * NN + n) * 16 + kq * 8);
  const ushort* wn = Wt + (size_t)n * 3072;
  const ushort* wwn = wwt + (size_t)n * 512;
  float4v accG[2] = {}, accW[2] = {};
#pragma unroll
  for (int t = 0; t < 2; ++t) {
    const int ob = (t * 16 + fm) * 96 + kq * 8;
    const short8 b0 = *(const short8*)(wn + ob);
    const short8 b1 = *(const short8*)(wn + ob + 32);
    const short8 b2 = *(const short8*)(wn + ob + 64);
    accG[t] = __builtin_amdgcn_mfma_f32_16x16x32_bf16(ax, b0, accG[t], 0, 0, 0);
    accG[t] = __builtin_amdgcn_mfma_f32_16x16x32_bf16(a1, b1, accG[t], 0, 0, 0);
    accG[t] = __builtin_amdgcn_mfma_f32_16x16x32_bf16(a2, b2, accG[t], 0, 0, 0);
    short8 bw = {};
    if (kq < 2) bw = *(const short8*)(wwn + (t * 16 + fm) * 16 + kq * 8);
    accW[t] = __builtin_amdgcn_mfma_f32_16x16x32_bf16(aw, bw, accW[t], 0, 0, 0);
  }
  const float w1a = ln1w[fm], w1b = ln1w[16 + fm];
  const float c1a = ln1b[fm], c1b = ln1b[16 + fm];
  const float w2a = ln2w[fm], w2b = ln2w[16 + fm];
  const float c2a = ln2b[fm], c2b = ln2b[16 + fm];
  const float* bn = biasN + (size_t)n * 64;
  const float bga = bn[fm], bgb = bn[16 + fm];
  const float bwa = bn[32 + fm], bwb = bn[48 + fm];
#pragma unroll
  for (int r = 0; r < 4; ++r) {
    const int b = kq * 4 + r;
    const float g0 = accG[0][r], g1 = accG[1][r];
    float s1 = g0 + g1, s2 = g0 * g0 + g1 * g1;
#pragma unroll
    for (int m = 1; m < 16; m <<= 1) { s1 += __shfl_xor(s1, m); s2 += __shfl_xor(s2, m); }
    const float mu = s1 * 0.03125f;
    const float rs = rsqrtf(s2 * 0.03125f - mu * mu + 1e-5f);
    const float h0 = accW[0][r], h1 = accW[1][r];
    float t1 = h0 + h1, t2 = h0 * h0 + h1 * h1;
#pragma unroll
    for (int m = 1; m < 16; m <<= 1) { t1 += __shfl_xor(t1, m); t2 += __shfl_xor(t2, m); }
    const float mu2 = t1 * 0.03125f;
    const float rs2 = rsqrtf(t2 * 0.03125f - mu2 * mu2 + 1e-5f);
    float* op = out + ((size_t)b * NN + n) * 64;
    op[fm]      = (g0 - mu) * rs * w1a + c1a + bga;
    op[16 + fm] = (g1 - mu) * rs * w1b + c1b + bgb;
    op[32 + fm] = (h0 - mu2) * rs2 * w2a + c2a + bwa;
    op[48 + fm] = (h1 - mu2) * rs2 * w2b + c2b + bwb;
  }
}

// ---------------------------------------------------------------------------
// Workspace map (fp32 slots), high-water 30,410,816 floats = 121.6 MB:
//   [0, 25M)              A fp32 -> P bf16 in place (row m = ushorts
//                         [m*10000+(m&1)*16, +5120) P, [m*10000+5160, +4096)
//                         8 bf16 split-K partial slabs)
//                         -> after reduce2: overlaid by Wt/wwt/biasN/xwc
//   [25.0M, 26.31072M)    XbT bf16 [512][5120]   (dead after GEMM1)
//   [26.31072M,27.62144M) Y1t bf16 [512][5120]   (dead after GEMM2)
//   [25.0M, 27.56M)       Y2f fp32 (reduce2 output, overlays XbT+Y1t)
//   [27.62144M,30.18144M) Y1f fp32
//   [30.18144M,30.378048M) wpP fp32 [64][3072]
//   [30.378048M,30.410816M) wwP fp32 [64][512]
// ---------------------------------------------------------------------------
extern "C" void kernel_launch(void* const* d_in, const int* in_sizes, int n_in,
                              void* d_out, int out_size, void* d_ws, size_t ws_size,
                              hipStream_t stream) {
  const float* x     = (const float*)d_in[0];
  const float* xwin  = (const float*)d_in[1];
  const float* emb   = (const float*)d_in[2];
  const float* wpool = (const float*)d_in[3];
  const float* wwin  = (const float*)d_in[4];
  const float* bpool = (const float*)d_in[5];
  const float* T     = (const float*)d_in[6];
  const float* ln1w  = (const float*)d_in[7];
  const float* ln1b  = (const float*)d_in[8];
  const float* ln2w  = (const float*)d_in[9];
  const float* ln2b  = (const float*)d_in[10];
  float* out = (float*)d_out;
  float* ws = (float*)d_ws;

  float*  A    = ws;
  ushort* P    = (ushort*)ws;
  ushort* XbT  = (ushort*)(ws + 25000000);
  ushort* Y1t  = (ushort*)(ws + 26310720);
  float*  Y1f  = ws + 27621440;
  float*  Y2f  = ws + 25000000;        // overlays XbT+Y1t after GEMM2
  ushort* Wt    = (ushort*)ws;         // [5000][3072] bf16, overlays P after reduce2
  ushort* wwt   = (ushort*)(ws + 15360000);  // [5000][512] bf16
  float*  biasN = ws + 17920000;
  float*  xwc   = ws + 18240000;       // overlays P rows — write after reduce2!
  float*  wpP   = ws + 30181440;       // [64][3072]
  float*  wwP   = ws + 30378048;       // [64][512]

  prep_kernel<<<11136, 256, 0, stream>>>(x, wpool, wwin, XbT, wpP, wwP);
  build_A_kernel<<<dim3(79, 79), dim3(16, 16), 0, stream>>>(emb, A);
  convert_P_kernel<<<NN, 256, 0, stream>>>(A);
  mfma_gemm_kernel<<<1280, 256, 0, stream>>>(P, XbT, P);
  reduce_kernel<<<dim3(8, 80), 256, 0, stream>>>(P, Y1f, Y1t, 1);
  mfma_gemm_kernel<<<1280, 256, 0, stream>>>(P, Y1t, P);
  reduce_kernel<<<dim3(8, 80), 256, 0, stream>>>(P, Y2f, (ushort*)nullptr, 0);
  emb_gemm_bf16_kernel<<<dim3(48, 157), 256, 0, stream>>>(emb, wpP, Wt, 3072);
  emb_gemm_bf16_kernel<<<dim3(8, 157), 256, 0, stream>>>(emb, wwP, wwt, 512);
  emb_gemm_kernel<<<dim3(1, 157), 256, 0, stream>>>(emb, bpool, biasN, NN, 64);
  window_combine_kernel<<<(BB * NN * 16 + 255) / 256, 256, 0, stream>>>(xwin, T, xwc);
  fuse_mfma_kernel<<<1250, 256, 0, stream>>>(x, Y1f, Y2f, Wt, wwt, biasN, xwc,
                                             ln1w, ln1b, ln2w, ln2b, out);
}